// Round 1
// baseline (4766.698 us; speedup 1.0000x reference)
//
#include <hip/hip_runtime.h>
#include <math.h>

// Problem constants (B=4, Cin=256, Cout=128, H=W=64)
#define NB 4
#define CI 256
#define CO 128
#define HW 4096

__device__ __forceinline__ float gelu_f(float x){
    return 0.5f * x * (1.0f + erff(x * 0.70710678118654752f));
}

// ---------------- per-channel avg/max over HW ----------------
__global__ void k_rowstats(const float* __restrict__ x, float* __restrict__ avg, float* __restrict__ mx){
    int row = blockIdx.x;                 // b*256+c, 1024 rows
    const float* p = x + (long long)row * HW;
    int t = threadIdx.x;
    float s = 0.f, m = -1e30f;
    for (int i = t; i < HW; i += 256){ float v = p[i]; s += v; m = fmaxf(m, v); }
    __shared__ float ss[256], sm[256];
    ss[t] = s; sm[t] = m; __syncthreads();
    for (int o = 128; o > 0; o >>= 1){
        if (t < o){ ss[t] += ss[t+o]; sm[t] = fmaxf(sm[t], sm[t+o]); }
        __syncthreads();
    }
    if (t == 0){ avg[row] = ss[0] / (float)HW; mx[row] = sm[0]; }
}

// ---------------- ChannelWeighting; also gp = avg*(1+s) ----------------
__global__ void k_cw(const float* __restrict__ avg, const float* __restrict__ mx,
                     const float* __restrict__ w1, const float* __restrict__ b1,
                     const float* __restrict__ lng, const float* __restrict__ lnb,
                     const float* __restrict__ w2, const float* __restrict__ b2,
                     float* __restrict__ sv, float* __restrict__ gp){
    int b = blockIdx.x, t = threadIdx.x;  // 4 blocks x 256
    __shared__ float o_s[256];
    __shared__ float h_s[128];
    __shared__ float stat[2];
    float a = avg[b*256 + t];
    o_s[t] = fabsf(a - mx[b*256 + t]) * a;
    __syncthreads();
    if (t < 128){
        float h = b1[t];
        for (int i = 0; i < 256; i++) h += o_s[i] * w1[t*256 + i];
        h_s[t] = h;
    }
    __syncthreads();
    if (t == 0){
        float s = 0.f, s2 = 0.f;
        for (int j = 0; j < 128; j++){ s += h_s[j]; s2 += h_s[j]*h_s[j]; }
        float mean = s / 128.f;
        float var  = s2 / 128.f - mean*mean;
        stat[0] = mean; stat[1] = rsqrtf(var + 1e-5f);   // nn.LayerNorm eps
    }
    __syncthreads();
    if (t < 128) h_s[t] = lng[t] * ((h_s[t] - stat[0]) * stat[1]) + lnb[t];
    __syncthreads();
    float z = b2[t];
    for (int j = 0; j < 128; j++) z += h_s[j] * w2[t*128 + j];
    float sig = 1.f / (1.f + __expf(-z));
    sv[b*256 + t] = sig;
    gp[b*256 + t] = a * (1.f + sig);      // mean(xc) = mean(x)*(1+s)
}

// ---------------- xc = x*(1+s) ----------------
__global__ void k_xc(const float* __restrict__ x, const float* __restrict__ s, float* __restrict__ xc){
    long long i = (long long)blockIdx.x * 256 + threadIdx.x;
    long long stride = (long long)gridDim.x * 256;
    const long long n = (long long)NB * CI * HW;
    for (; i < n; i += stride) xc[i] = x[i] * (1.f + s[i >> 12]);
}

// ---------------- tiled f32 GEMM: C[b] = A(MxK) @ B[b](KxN) (+bias) ----------------
__global__ void k_gemm(const float* __restrict__ A, const float* __restrict__ Bm,
                       float* __restrict__ Cm, const float* __restrict__ bias,
                       int M, int N, int K, long long bsB, long long bsC){
    int b = blockIdx.z;
    const float* Bp = Bm + (long long)b * bsB;
    float* Cp = Cm + (long long)b * bsC;
    int n0 = blockIdx.x * 64, m0 = blockIdx.y * 64;
    __shared__ float As[16][64];
    __shared__ float Bs[16][65];
    int t = threadIdx.x;
    int tx = t & 15, ty = t >> 4;
    float acc[4][4] = {};
    for (int k0 = 0; k0 < K; k0 += 16){
        #pragma unroll
        for (int e = 0; e < 4; e++){
            int idx = t + e*256;
            int kk = idx >> 6, col = idx & 63;
            As[kk][col] = A[(long long)(m0+col)*K + (k0+kk)];
            Bs[kk][col] = Bp[(long long)(k0+kk)*N + (n0+col)];
        }
        __syncthreads();
        #pragma unroll
        for (int kk = 0; kk < 16; kk++){
            float av[4], bv[4];
            #pragma unroll
            for (int i = 0; i < 4; i++) av[i] = As[kk][ty*4 + i];
            #pragma unroll
            for (int j = 0; j < 4; j++) bv[j] = Bs[kk][tx*4 + j];
            #pragma unroll
            for (int i = 0; i < 4; i++)
                #pragma unroll
                for (int j = 0; j < 4; j++) acc[i][j] += av[i]*bv[j];
        }
        __syncthreads();
    }
    #pragma unroll
    for (int i = 0; i < 4; i++){
        int m = m0 + ty*4 + i;
        float bb = bias ? bias[m] : 0.f;
        #pragma unroll
        for (int j = 0; j < 4; j++)
            Cp[(long long)m*N + (n0 + tx*4 + j)] = acc[i][j] + bb;
    }
}

// ---------------- 3x3 dilated conv as implicit GEMM (M=256,N=4096,K=2304) ----------------
__global__ void k_conv3(const float* __restrict__ W, const float* __restrict__ Bm,
                        float* __restrict__ Cm, int d, long long bsB, long long bsC){
    int b = blockIdx.z;
    const float* Bp = Bm + (long long)b * bsB;
    float* Cp = Cm + (long long)b * bsC;
    int n0 = blockIdx.x * 64, m0 = blockIdx.y * 64;
    int y = n0 >> 6;                        // one image row per 64-wide n-tile
    __shared__ float As[16][64];
    __shared__ float Bs[16][65];
    int t = threadIdx.x;
    int tx = t & 15, ty = t >> 4;
    float acc[4][4] = {};
    for (int k0 = 0; k0 < 2304; k0 += 16){
        int tap = k0 >> 8;                  // k = tap*256 + ci; tap constant in tile
        int dy = tap/3 - 1, dx = tap%3 - 1;
        int ys = y + dy*d;
        bool yok = (unsigned)ys < 64u;
        #pragma unroll
        for (int e = 0; e < 4; e++){
            int idx = t + e*256;
            int kk = idx >> 6, col = idx & 63;
            int ci = (k0 + kk) & 255;
            As[kk][col] = W[((long long)(m0+col)*256 + ci)*9 + tap];
            int xs = col + dx*d;
            float v = 0.f;
            if (yok && (unsigned)xs < 64u) v = Bp[(long long)ci*HW + ys*64 + xs];
            Bs[kk][col] = v;
        }
        __syncthreads();
        #pragma unroll
        for (int kk = 0; kk < 16; kk++){
            float av[4], bv[4];
            #pragma unroll
            for (int i = 0; i < 4; i++) av[i] = As[kk][ty*4 + i];
            #pragma unroll
            for (int j = 0; j < 4; j++) bv[j] = Bs[kk][tx*4 + j];
            #pragma unroll
            for (int i = 0; i < 4; i++)
                #pragma unroll
                for (int j = 0; j < 4; j++) acc[i][j] += av[i]*bv[j];
        }
        __syncthreads();
    }
    #pragma unroll
    for (int i = 0; i < 4; i++){
        int m = m0 + ty*4 + i;
        #pragma unroll
        for (int j = 0; j < 4; j++)
            Cp[(long long)m*HW + (n0 + tx*4 + j)] = acc[i][j];
    }
}

// ---------------- channels-first LayerNorm + exact GELU, in place ----------------
__global__ void k_ln_gelu(float* __restrict__ Y, const float* __restrict__ g, const float* __restrict__ bta,
                          int C, long long bstride, float eps){
    int b = blockIdx.y;
    int p = blockIdx.x * 256 + threadIdx.x;       // position in HW
    float* base = Y + (long long)b * bstride + p;
    float s = 0.f, s2 = 0.f;
    for (int c = 0; c < C; c++){ float v = base[(long long)c * HW]; s += v; s2 += v*v; }
    float mean = s / (float)C;
    float var  = s2 / (float)C - mean*mean;       // biased, as in reference
    float inv  = rsqrtf(var + eps);
    for (int c = 0; c < C; c++){
        float v = base[(long long)c * HW];
        float h = g[c] * ((v - mean) * inv) + bta[c];
        base[(long long)c * HW] = gelu_f(h);
    }
}

// ---------------- pooled branch: conv1x1(gp) -> LN -> GELU ----------------
__global__ void k_pool(const float* __restrict__ gp, const float* __restrict__ w,
                       const float* __restrict__ g, const float* __restrict__ bta,
                       float* __restrict__ bp){
    int b = blockIdx.x, t = threadIdx.x;   // 4 blocks x 256
    __shared__ float z_s[256];
    __shared__ float stat[2];
    float z = 0.f;
    for (int c = 0; c < 256; c++) z += gp[b*256 + c] * w[t*256 + c];
    z_s[t] = z;
    __syncthreads();
    if (t == 0){
        float s = 0.f, s2 = 0.f;
        for (int c = 0; c < 256; c++){ s += z_s[c]; s2 += z_s[c]*z_s[c]; }
        float mean = s / 256.f, var = s2 / 256.f - mean*mean;
        stat[0] = mean; stat[1] = rsqrtf(var + 1e-6f);
    }
    __syncthreads();
    float h = g[t] * ((z - stat[0]) * stat[1]) + bta[t];
    bp[b*256 + t] = gelu_f(h);
}

// ---------------- broadcast pooled branch into cat rows 1024..1279 ----------------
__global__ void k_bcast(const float* __restrict__ bp, float* __restrict__ cat){
    long long i = (long long)blockIdx.x * 256 + threadIdx.x;
    long long stride = (long long)gridDim.x * 256;
    const long long n = (long long)NB * 256 * HW;
    for (; i < n; i += stride){
        int p = (int)(i & 4095);
        int c = (int)((i >> 12) & 255);
        int b = (int)(i >> 20);
        cat[(long long)b*1280*HW + (long long)(1024 + c)*HW + p] = bp[b*256 + c];
    }
}

// ---------------- attention pass 1: per-row softmax stats (m,l) over p ----------------
__global__ void k_attn_stats(const float* __restrict__ Q, const float* __restrict__ P,
                             float* __restrict__ mrow, float* __restrict__ lrow){
    int b = blockIdx.y;
    int k0 = blockIdx.x * 64;
    const float* Qb = Q + (long long)b * CO * HW;
    const float* Pb = P + (long long)b * CO * HW;
    __shared__ float Qs[CO][64];   // 32 KB
    __shared__ float Ps[CO][32];   // 16 KB
    __shared__ float Ss[64][33];   // 8.4 KB
    int t = threadIdx.x;
    for (int e = t; e < CO*64; e += 256){
        int c = e >> 6, k = e & 63;
        Qs[c][k] = Qb[(long long)c*HW + k0 + k];
    }
    float rm = -1e30f, rl = 0.f;
    const float scale = 0.015625f;            // 1/sqrt(4096)
    int krow = t >> 2;                        // 0..63
    int pb = (t & 3) * 8;                     // 0,8,16,24
    for (int p0 = 0; p0 < HW; p0 += 32){
        for (int e = t; e < CO*32; e += 256){
            int c = e >> 5, p = e & 31;
            Ps[c][p] = Pb[(long long)c*HW + p0 + p];
        }
        __syncthreads();
        float acc[8] = {};
        for (int c = 0; c < CO; c++){
            float q = Qs[c][krow];
            #pragma unroll
            for (int j = 0; j < 8; j++) acc[j] += q * Ps[c][pb + j];
        }
        #pragma unroll
        for (int j = 0; j < 8; j++) Ss[krow][pb + j] = acc[j] * scale;
        __syncthreads();
        if (t < 64){
            float mt = -1e30f;
            #pragma unroll
            for (int p = 0; p < 32; p++) mt = fmaxf(mt, Ss[t][p]);
            float mn = fmaxf(rm, mt);
            float sum = 0.f;
            #pragma unroll
            for (int p = 0; p < 32; p++) sum += __expf(Ss[t][p] - mn);
            rl = rl * __expf(rm - mn) + sum;
            rm = mn;
        }
    }
    if (t < 64){
        mrow[(long long)b*HW + k0 + t] = rm;
        lrow[(long long)b*HW + k0 + t] = rl;
    }
}

// ---------------- attention pass 2: O = P @ A + xa (A recomputed tilewise) ----------------
__global__ void k_attn_apply(const float* __restrict__ Q, const float* __restrict__ P,
                             const float* __restrict__ mrow, const float* __restrict__ lrow,
                             float* __restrict__ O){
    int b = blockIdx.y;
    int j0 = blockIdx.x * 32;
    const float* Qb = Q + (long long)b * CO * HW;
    const float* Pb = P + (long long)b * CO * HW;
    const float* mb = mrow + (long long)b * HW;
    const float* lb = lrow + (long long)b * HW;
    __shared__ float Pj[CO][32];   // 16 KB (persistent)
    __shared__ float Qk[CO][32];   // 16 KB
    __shared__ float Pk[CO][33];   // 16.5 KB
    __shared__ float Es[32][33];   // 4.2 KB
    int t = threadIdx.x;
    for (int e = t; e < CO*32; e += 256){
        int c = e >> 5, j = e & 31;
        Pj[c][j] = Pb[(long long)c*HW + j0 + j];
    }
    float acc[4][4] = {};
    int cb = (t >> 3) << 2;        // c base: 0..124 step 4
    int jb = (t & 7) * 4;          // j base: 0..28
    int ks = t >> 3;               // S row: 0..31
    const float scale = 0.015625f;
    for (int k0 = 0; k0 < HW; k0 += 32){
        __syncthreads();
        for (int e = t; e < CO*32; e += 256){
            int c = e >> 5, k = e & 31;
            Qk[c][k] = Qb[(long long)c*HW + k0 + k];
            Pk[c][k] = Pb[(long long)c*HW + k0 + k];
        }
        __syncthreads();
        float sa[4] = {};
        for (int c = 0; c < CO; c++){
            float q = Qk[c][ks];
            #pragma unroll
            for (int j = 0; j < 4; j++) sa[j] += q * Pj[c][jb + j];
        }
        float mk = mb[k0 + ks];
        float il = 1.f / lb[k0 + ks];
        #pragma unroll
        for (int j = 0; j < 4; j++) Es[ks][jb + j] = __expf(sa[j]*scale - mk) * il;
        __syncthreads();
        #pragma unroll
        for (int kk = 0; kk < 32; kk++){
            float ev[4];
            #pragma unroll
            for (int j = 0; j < 4; j++) ev[j] = Es[kk][jb + j];
            #pragma unroll
            for (int i = 0; i < 4; i++){
                float pv = Pk[cb + i][kk];
                #pragma unroll
                for (int j = 0; j < 4; j++) acc[i][j] += pv * ev[j];
            }
        }
    }
    for (int i = 0; i < 4; i++)
        for (int j = 0; j < 4; j++){
            long long idx = (long long)(cb + i)*HW + j0 + jb + j;
            O[(long long)b*CO*HW + idx] = acc[i][j] + Qb[idx];   // O = L + xa (Q is xa)
        }
}

extern "C" void kernel_launch(void* const* d_in, const int* in_sizes, int n_in,
                              void* d_out, int out_size, void* d_ws, size_t ws_size,
                              hipStream_t stream) {
    const float* x       = (const float*)d_in[0];
    const float* conv1_w = (const float*)d_in[1];
    const float* conv1_b = (const float*)d_in[2];
    const float* conv2_w = (const float*)d_in[3];
    const float* conv2_b = (const float*)d_in[4];
    const float* cw_w1   = (const float*)d_in[5];
    const float* cw_b1   = (const float*)d_in[6];
    const float* cw_g    = (const float*)d_in[7];
    const float* cw_bt   = (const float*)d_in[8];
    const float* cw_w2   = (const float*)d_in[9];
    const float* cw_b2   = (const float*)d_in[10];
    const float* a0_w    = (const float*)d_in[11];
    const float* a0_g    = (const float*)d_in[12];
    const float* a0_b    = (const float*)d_in[13];
    const float* a1_w    = (const float*)d_in[14];
    const float* a1_g    = (const float*)d_in[15];
    const float* a1_b    = (const float*)d_in[16];
    const float* a2_w    = (const float*)d_in[17];
    const float* a2_g    = (const float*)d_in[18];
    const float* a2_b    = (const float*)d_in[19];
    const float* a3_w    = (const float*)d_in[20];
    const float* a3_g    = (const float*)d_in[21];
    const float* a3_b    = (const float*)d_in[22];
    const float* ap_w    = (const float*)d_in[23];
    const float* ap_g    = (const float*)d_in[24];
    const float* ap_b    = (const float*)d_in[25];
    const float* pj_w    = (const float*)d_in[26];
    const float* pj_g    = (const float*)d_in[27];
    const float* pj_b    = (const float*)d_in[28];
    float* out = (float*)d_out;

    // workspace layout (floats); proj aliases xc, O aliases cat (lifetimes disjoint)
    float* ws   = (float*)d_ws;
    float* avg  = ws;                 // 1024
    float* mx   = avg  + 1024;        // 1024
    float* sv   = mx   + 1024;        // 1024
    float* gp   = sv   + 1024;        // 1024
    float* bp   = gp   + 1024;        // 1024
    float* mrow = bp   + 1024;        // 16384
    float* lrow = mrow + 16384;       // 16384
    float* x1   = lrow + 16384;       // 4*128*4096 = 2,097,152
    float* xc   = x1   + 2097152;     // 4*256*4096 = 4,194,304
    float* cat  = xc   + 4194304;     // 4*1280*4096 = 20,971,520
    float* xa   = cat  + 20971520;    // 2,097,152   (end: ~112 MB)
    float* proj = xc;                 // alias: xc dead after conv branches
    float* Obuf = cat;                // alias: cat dead after proj GEMM

    const long long bsX  = (long long)CI * HW;    // 256*4096
    const long long bsXo = (long long)CO * HW;    // 128*4096
    const long long bsCat= 1280LL * HW;

    // 1. channel stats + channel weighting
    k_rowstats<<<dim3(NB*CI), 256, 0, stream>>>(x, avg, mx);
    k_cw<<<dim3(NB), 256, 0, stream>>>(avg, mx, cw_w1, cw_b1, cw_g, cw_bt, cw_w2, cw_b2, sv, gp);
    k_xc<<<dim3(4096), 256, 0, stream>>>(x, sv, xc);

    // 2. x1 = conv1(x) + b
    k_gemm<<<dim3(64, 2, NB), 256, 0, stream>>>(conv1_w, x, x1, conv1_b, 128, HW, 256, bsX, bsXo);

    // 3. ASPP branches into cat
    k_gemm <<<dim3(64, 4, NB), 256, 0, stream>>>(a0_w, xc, cat,              nullptr, 256, HW, 256, bsX, bsCat);
    k_conv3<<<dim3(64, 4, NB), 256, 0, stream>>>(a1_w, xc, cat + 256*HW,     3, bsX, bsCat);
    k_conv3<<<dim3(64, 4, NB), 256, 0, stream>>>(a2_w, xc, cat + 512*HW,     6, bsX, bsCat);
    k_conv3<<<dim3(64, 4, NB), 256, 0, stream>>>(a3_w, xc, cat + 768*HW,     9, bsX, bsCat);
    k_ln_gelu<<<dim3(16, NB), 256, 0, stream>>>(cat,            a0_g, a0_b, 256, bsCat, 1e-6f);
    k_ln_gelu<<<dim3(16, NB), 256, 0, stream>>>(cat + 256*HW,   a1_g, a1_b, 256, bsCat, 1e-6f);
    k_ln_gelu<<<dim3(16, NB), 256, 0, stream>>>(cat + 512*HW,   a2_g, a2_b, 256, bsCat, 1e-6f);
    k_ln_gelu<<<dim3(16, NB), 256, 0, stream>>>(cat + 768*HW,   a3_g, a3_b, 256, bsCat, 1e-6f);
    k_pool<<<dim3(NB), 256, 0, stream>>>(gp, ap_w, ap_g, ap_b, bp);
    k_bcast<<<dim3(4096), 256, 0, stream>>>(bp, cat);

    // 4. proj = GELU(LN(conv1x1(cat)))   (proj aliases xc)
    k_gemm<<<dim3(64, 4, NB), 256, 0, stream>>>(pj_w, cat, proj, nullptr, 256, HW, 1280, bsCat, bsX);
    k_ln_gelu<<<dim3(16, NB), 256, 0, stream>>>(proj, pj_g, pj_b, 256, bsX, 1e-6f);

    // 5. xa = conv1(proj) + b
    k_gemm<<<dim3(64, 2, NB), 256, 0, stream>>>(conv1_w, proj, xa, conv1_b, 128, HW, 256, bsX, bsXo);

    // 6. attention (two-pass online softmax; O aliases cat)
    k_attn_stats<<<dim3(64, NB), 256, 0, stream>>>(xa, x1, mrow, lrow);
    k_attn_apply<<<dim3(128, NB), 256, 0, stream>>>(xa, x1, mrow, lrow, Obuf);

    // 7. out = conv2(O) + b
    k_gemm<<<dim3(64, 4, NB), 256, 0, stream>>>(conv2_w, Obuf, out, conv2_b, 256, HW, 128, bsXo, bsX);

    (void)in_sizes; (void)n_in; (void)out_size; (void)ws_size;
}

// Round 2
// 2587.502 us; speedup vs baseline: 1.8422x; 1.8422x over previous
//
#include <hip/hip_runtime.h>
#include <hip/hip_bf16.h>
#include <math.h>

// Problem constants (B=4, Cin=256, Cout=128, H=W=64)
#define NB 4
#define CI 256
#define CO 128
#define HW 4096

typedef __attribute__((ext_vector_type(8))) short s8v;   // 8 bf16 = 4 VGPRs (MFMA A/B frag)
typedef __attribute__((ext_vector_type(4))) short s4v;
typedef __attribute__((ext_vector_type(4))) float f4v;   // MFMA C/D frag

__device__ __forceinline__ float gelu_f(float x){
    return 0.5f * x * (1.0f + erff(x * 0.70710678118654752f));
}

__device__ __forceinline__ unsigned short f2bf(float f){
    __hip_bfloat16 h = __float2bfloat16(f);   // RNE
    return *reinterpret_cast<unsigned short*>(&h);
}

// ---------------- per-channel avg/max over HW ----------------
__global__ void k_rowstats(const float* __restrict__ x, float* __restrict__ avg, float* __restrict__ mx){
    int row = blockIdx.x;                 // b*256+c, 1024 rows
    const float* p = x + (long long)row * HW;
    int t = threadIdx.x;
    float s = 0.f, m = -1e30f;
    for (int i = t; i < HW; i += 256){ float v = p[i]; s += v; m = fmaxf(m, v); }
    __shared__ float ss[256], sm[256];
    ss[t] = s; sm[t] = m; __syncthreads();
    for (int o = 128; o > 0; o >>= 1){
        if (t < o){ ss[t] += ss[t+o]; sm[t] = fmaxf(sm[t], sm[t+o]); }
        __syncthreads();
    }
    if (t == 0){ avg[row] = ss[0] / (float)HW; mx[row] = sm[0]; }
}

// ---------------- ChannelWeighting; also gp = avg*(1+s) ----------------
__global__ void k_cw(const float* __restrict__ avg, const float* __restrict__ mx,
                     const float* __restrict__ w1, const float* __restrict__ b1,
                     const float* __restrict__ lng, const float* __restrict__ lnb,
                     const float* __restrict__ w2, const float* __restrict__ b2,
                     float* __restrict__ sv, float* __restrict__ gp){
    int b = blockIdx.x, t = threadIdx.x;  // 4 blocks x 256
    __shared__ float o_s[256];
    __shared__ float h_s[128];
    __shared__ float stat[2];
    float a = avg[b*256 + t];
    o_s[t] = fabsf(a - mx[b*256 + t]) * a;
    __syncthreads();
    if (t < 128){
        float h = b1[t];
        for (int i = 0; i < 256; i++) h += o_s[i] * w1[t*256 + i];
        h_s[t] = h;
    }
    __syncthreads();
    if (t == 0){
        float s = 0.f, s2 = 0.f;
        for (int j = 0; j < 128; j++){ s += h_s[j]; s2 += h_s[j]*h_s[j]; }
        float mean = s / 128.f;
        float var  = s2 / 128.f - mean*mean;
        stat[0] = mean; stat[1] = rsqrtf(var + 1e-5f);   // nn.LayerNorm eps
    }
    __syncthreads();
    if (t < 128) h_s[t] = lng[t] * ((h_s[t] - stat[0]) * stat[1]) + lnb[t];
    __syncthreads();
    float z = b2[t];
    for (int j = 0; j < 128; j++) z += h_s[j] * w2[t*128 + j];
    float sig = 1.f / (1.f + __expf(-z));
    sv[b*256 + t] = sig;
    gp[b*256 + t] = a * (1.f + sig);      // mean(xc) = mean(x)*(1+s)
}

// ---------------- xc = x*(1+s) ----------------
__global__ void k_xc(const float* __restrict__ x, const float* __restrict__ s, float* __restrict__ xc){
    long long i = (long long)blockIdx.x * 256 + threadIdx.x;
    long long stride = (long long)gridDim.x * 256;
    const long long n = (long long)NB * CI * HW;
    for (; i < n; i += stride) xc[i] = x[i] * (1.f + s[i >> 12]);
}

// ---------------- tiled f32 GEMM: C[b] = A(MxK) @ B[b](KxN) (+bias) ----------------
__global__ void k_gemm(const float* __restrict__ A, const float* __restrict__ Bm,
                       float* __restrict__ Cm, const float* __restrict__ bias,
                       int M, int N, int K, long long bsB, long long bsC){
    int b = blockIdx.z;
    const float* Bp = Bm + (long long)b * bsB;
    float* Cp = Cm + (long long)b * bsC;
    int n0 = blockIdx.x * 64, m0 = blockIdx.y * 64;
    __shared__ float As[16][64];
    __shared__ float Bs[16][65];
    int t = threadIdx.x;
    int tx = t & 15, ty = t >> 4;
    float acc[4][4] = {};
    for (int k0 = 0; k0 < K; k0 += 16){
        #pragma unroll
        for (int e = 0; e < 4; e++){
            int idx = t + e*256;
            int kk = idx >> 6, col = idx & 63;
            As[kk][col] = A[(long long)(m0+col)*K + (k0+kk)];
            Bs[kk][col] = Bp[(long long)(k0+kk)*N + (n0+col)];
        }
        __syncthreads();
        #pragma unroll
        for (int kk = 0; kk < 16; kk++){
            float av[4], bv[4];
            #pragma unroll
            for (int i = 0; i < 4; i++) av[i] = As[kk][ty*4 + i];
            #pragma unroll
            for (int j = 0; j < 4; j++) bv[j] = Bs[kk][tx*4 + j];
            #pragma unroll
            for (int i = 0; i < 4; i++)
                #pragma unroll
                for (int j = 0; j < 4; j++) acc[i][j] += av[i]*bv[j];
        }
        __syncthreads();
    }
    #pragma unroll
    for (int i = 0; i < 4; i++){
        int m = m0 + ty*4 + i;
        float bb = bias ? bias[m] : 0.f;
        #pragma unroll
        for (int j = 0; j < 4; j++)
            Cp[(long long)m*N + (n0 + tx*4 + j)] = acc[i][j] + bb;
    }
}

// ---------------- 3x3 dilated conv as implicit GEMM (M=256,N=4096,K=2304) ----------------
__global__ void k_conv3(const float* __restrict__ W, const float* __restrict__ Bm,
                        float* __restrict__ Cm, int d, long long bsB, long long bsC){
    int b = blockIdx.z;
    const float* Bp = Bm + (long long)b * bsB;
    float* Cp = Cm + (long long)b * bsC;
    int n0 = blockIdx.x * 64, m0 = blockIdx.y * 64;
    int y = n0 >> 6;                        // one image row per 64-wide n-tile
    __shared__ float As[16][64];
    __shared__ float Bs[16][65];
    int t = threadIdx.x;
    int tx = t & 15, ty = t >> 4;
    float acc[4][4] = {};
    for (int k0 = 0; k0 < 2304; k0 += 16){
        int tap = k0 >> 8;                  // k = tap*256 + ci; tap constant in tile
        int dy = tap/3 - 1, dx = tap%3 - 1;
        int ys = y + dy*d;
        bool yok = (unsigned)ys < 64u;
        #pragma unroll
        for (int e = 0; e < 4; e++){
            int idx = t + e*256;
            int kk = idx >> 6, col = idx & 63;
            int ci = (k0 + kk) & 255;
            As[kk][col] = W[((long long)(m0+col)*256 + ci)*9 + tap];
            int xs = col + dx*d;
            float v = 0.f;
            if (yok && (unsigned)xs < 64u) v = Bp[(long long)ci*HW + ys*64 + xs];
            Bs[kk][col] = v;
        }
        __syncthreads();
        #pragma unroll
        for (int kk = 0; kk < 16; kk++){
            float av[4], bv[4];
            #pragma unroll
            for (int i = 0; i < 4; i++) av[i] = As[kk][ty*4 + i];
            #pragma unroll
            for (int j = 0; j < 4; j++) bv[j] = Bs[kk][tx*4 + j];
            #pragma unroll
            for (int i = 0; i < 4; i++)
                #pragma unroll
                for (int j = 0; j < 4; j++) acc[i][j] += av[i]*bv[j];
        }
        __syncthreads();
    }
    #pragma unroll
    for (int i = 0; i < 4; i++){
        int m = m0 + ty*4 + i;
        #pragma unroll
        for (int j = 0; j < 4; j++)
            Cp[(long long)m*HW + (n0 + tx*4 + j)] = acc[i][j];
    }
}

// ---------------- channels-first LayerNorm + exact GELU, in place ----------------
__global__ void k_ln_gelu(float* __restrict__ Y, const float* __restrict__ g, const float* __restrict__ bta,
                          int C, long long bstride, float eps){
    int b = blockIdx.y;
    int p = blockIdx.x * 256 + threadIdx.x;       // position in HW
    float* base = Y + (long long)b * bstride + p;
    float s = 0.f, s2 = 0.f;
    for (int c = 0; c < C; c++){ float v = base[(long long)c * HW]; s += v; s2 += v*v; }
    float mean = s / (float)C;
    float var  = s2 / (float)C - mean*mean;       // biased, as in reference
    float inv  = rsqrtf(var + eps);
    for (int c = 0; c < C; c++){
        float v = base[(long long)c * HW];
        float h = g[c] * ((v - mean) * inv) + bta[c];
        base[(long long)c * HW] = gelu_f(h);
    }
}

// ---------------- pooled branch: conv1x1(gp) -> LN -> GELU ----------------
__global__ void k_pool(const float* __restrict__ gp, const float* __restrict__ w,
                       const float* __restrict__ g, const float* __restrict__ bta,
                       float* __restrict__ bp){
    int b = blockIdx.x, t = threadIdx.x;   // 4 blocks x 256
    __shared__ float z_s[256];
    __shared__ float stat[2];
    float z = 0.f;
    for (int c = 0; c < 256; c++) z += gp[b*256 + c] * w[t*256 + c];
    z_s[t] = z;
    __syncthreads();
    if (t == 0){
        float s = 0.f, s2 = 0.f;
        for (int c = 0; c < 256; c++){ s += z_s[c]; s2 += z_s[c]*z_s[c]; }
        float mean = s / 256.f, var = s2 / 256.f - mean*mean;
        stat[0] = mean; stat[1] = rsqrtf(var + 1e-6f);
    }
    __syncthreads();
    float h = g[t] * ((z - stat[0]) * stat[1]) + bta[t];
    bp[b*256 + t] = gelu_f(h);
}

// ---------------- broadcast pooled branch into cat rows 1024..1279 ----------------
__global__ void k_bcast(const float* __restrict__ bp, float* __restrict__ cat){
    long long i = (long long)blockIdx.x * 256 + threadIdx.x;
    long long stride = (long long)gridDim.x * 256;
    const long long n = (long long)NB * 256 * HW;
    for (; i < n; i += stride){
        int p = (int)(i & 4095);
        int c = (int)((i >> 12) & 255);
        int b = (int)(i >> 20);
        cat[(long long)b*1280*HW + (long long)(1024 + c)*HW + p] = bp[b*256 + c];
    }
}

// ---------------- cast f32 [CO][HW] -> bf16 same layout (optional) + transposed [HW][CO] ----------------
__global__ void k_castT(const float* __restrict__ X, unsigned short* __restrict__ Xbf,
                        unsigned short* __restrict__ XT){
    int b = blockIdx.z;
    int h0 = blockIdx.x * 64, c0 = blockIdx.y * 64;
    const float* Xb = X + ((long long)b*CO + c0) * HW + h0;
    __shared__ unsigned short T[64][66];
    int t = threadIdx.x;
    int hl = t & 63, cs = t >> 6;
    #pragma unroll
    for (int r = 0; r < 16; r++){
        int c = cs*16 + r;
        unsigned short v = f2bf(Xb[(long long)c*HW + hl]);
        T[c][hl] = v;
        if (Xbf) Xbf[((long long)b*CO + c0 + c)*HW + h0 + hl] = v;
    }
    __syncthreads();
    int cl = t & 63, hs = t >> 6;
    #pragma unroll
    for (int r = 0; r < 16; r++){
        int h = hs*16 + r;
        XT[((long long)b*HW + h0 + h)*CO + c0 + cl] = T[cl][h];
    }
}

// ---------------- attention pass 1 (MFMA bf16): per-row (m,l) over p ----------------
// S[k,j] = sum_c Q[c,k] P[c,j] / 64.  A = QT rows k (A[m][kk], m=lane&15, kk=quad*8+i),
// B = PT rows j (B[kk][n], n=lane&15).  C/D: col=lane&15, row=quad*4+reg.
__global__ void k_attn_stats_m(const unsigned short* __restrict__ QT,
                               const unsigned short* __restrict__ PT,
                               float* __restrict__ mrow, float* __restrict__ lrow){
    int b = blockIdx.y, k0 = blockIdx.x * 64;
    const unsigned short* QTb = QT + (long long)b * HW * CO;
    const unsigned short* PTb = PT + (long long)b * HW * CO;
    __shared__ unsigned short Qs[64][136];   // +8 pad: 272B pitch, 16B-aligned frags, 2-way banks
    __shared__ unsigned short Ps[64][136];
    int t = threadIdx.x;
    int w = t >> 6, lane = t & 63, m = lane & 15, q = lane >> 4;
    {
        int r = t >> 2, ch = t & 3;
        const uint4* src = (const uint4*)(QTb + (long long)(k0 + r) * CO + ch * 32);
        uint4* dst = (uint4*)&Qs[r][ch * 32];
        #pragma unroll
        for (int i = 0; i < 4; i++) dst[i] = src[i];
    }
    __syncthreads();
    s8v a[4];
    #pragma unroll
    for (int ks = 0; ks < 4; ks++) a[ks] = *(const s8v*)&Qs[w*16 + m][q*8 + ks*32];
    float rm[4], rl[4];
    #pragma unroll
    for (int r = 0; r < 4; r++){ rm[r] = -1e30f; rl[r] = 0.f; }
    const float scale = 0.015625f;           // 1/sqrt(4096)
    for (int j0 = 0; j0 < HW; j0 += 64){
        __syncthreads();
        {
            int r = t >> 2, ch = t & 3;
            const uint4* src = (const uint4*)(PTb + (long long)(j0 + r) * CO + ch * 32);
            uint4* dst = (uint4*)&Ps[r][ch * 32];
            #pragma unroll
            for (int i = 0; i < 4; i++) dst[i] = src[i];
        }
        __syncthreads();
        float sv[4][4];
        #pragma unroll
        for (int ct = 0; ct < 4; ct++){
            f4v acc = {0.f,0.f,0.f,0.f};
            #pragma unroll
            for (int ks = 0; ks < 4; ks++){
                s8v bv = *(const s8v*)&Ps[ct*16 + m][q*8 + ks*32];
                acc = __builtin_amdgcn_mfma_f32_16x16x32_bf16(a[ks], bv, acc, 0, 0, 0);
            }
            #pragma unroll
            for (int r = 0; r < 4; r++) sv[ct][r] = acc[r] * scale;
        }
        #pragma unroll
        for (int r = 0; r < 4; r++){
            float mx = fmaxf(fmaxf(sv[0][r], sv[1][r]), fmaxf(sv[2][r], sv[3][r]));
            #pragma unroll
            for (int msk = 1; msk < 16; msk <<= 1) mx = fmaxf(mx, __shfl_xor(mx, msk));
            float nm = fmaxf(rm[r], mx);
            float se = __expf(sv[0][r]-nm) + __expf(sv[1][r]-nm)
                     + __expf(sv[2][r]-nm) + __expf(sv[3][r]-nm);
            #pragma unroll
            for (int msk = 1; msk < 16; msk <<= 1) se += __shfl_xor(se, msk);
            rl[r] = rl[r] * __expf(rm[r] - nm) + se;
            rm[r] = nm;
        }
    }
    if (m == 0){
        #pragma unroll
        for (int r = 0; r < 4; r++){
            int k = k0 + w*16 + q*4 + r;
            mrow[(long long)b*HW + k] = rm[r];
            lrow[(long long)b*HW + k] = rl[r];
        }
    }
}

// ---------------- attention pass 2 (MFMA bf16): O = P @ A + xa ----------------
__global__ void k_attn_apply_m(const unsigned short* __restrict__ QT,
                               const unsigned short* __restrict__ PT,
                               const unsigned short* __restrict__ Pb,
                               const float* __restrict__ mrow, const float* __restrict__ lrow,
                               const float* __restrict__ xa, float* __restrict__ O){
    int b = blockIdx.y, j0 = blockIdx.x * 64;
    const unsigned short* QTb = QT + (long long)b * HW * CO;
    const unsigned short* PTb = PT + (long long)b * HW * CO;
    const unsigned short* Pbb = Pb + (long long)b * CO * HW;
    const float* mb = mrow + (long long)b * HW;
    const float* lb = lrow + (long long)b * HW;
    __shared__ unsigned short Pjs[64][136];  // PT j-tile (fixed)
    __shared__ unsigned short Qks[64][136];  // QT k-tile (streamed)
    __shared__ unsigned short Pcs[128][72];  // P [c][k-tile] (streamed)
    __shared__ unsigned short Et[64][72];    // E^T [j][k]
    int t = threadIdx.x;
    int w = t >> 6, lane = t & 63, m = lane & 15, q = lane >> 4;
    {
        int r = t >> 2, ch = t & 3;
        const uint4* src = (const uint4*)(PTb + (long long)(j0 + r) * CO + ch * 32);
        uint4* dst = (uint4*)&Pjs[r][ch * 32];
        #pragma unroll
        for (int i = 0; i < 4; i++) dst[i] = src[i];
    }
    __syncthreads();
    s8v bj[4][4];                            // B-frags for S (fixed j-tile)
    #pragma unroll
    for (int ct = 0; ct < 4; ct++)
        #pragma unroll
        for (int ks = 0; ks < 4; ks++)
            bj[ct][ks] = *(const s8v*)&Pjs[ct*16 + m][q*8 + ks*32];
    f4v accL[2][4];
    #pragma unroll
    for (int mt = 0; mt < 2; mt++)
        #pragma unroll
        for (int ct = 0; ct < 4; ct++){ f4v z = {0.f,0.f,0.f,0.f}; accL[mt][ct] = z; }
    const float scale = 0.015625f;
    for (int k0 = 0; k0 < HW; k0 += 64){
        __syncthreads();
        {
            int r = t >> 2, ch = t & 3;
            const uint4* src = (const uint4*)(QTb + (long long)(k0 + r) * CO + ch * 32);
            uint4* dst = (uint4*)&Qks[r][ch * 32];
            #pragma unroll
            for (int i = 0; i < 4; i++) dst[i] = src[i];
        }
        {
            int c = t >> 1, hf = t & 1;
            const uint4* src = (const uint4*)(Pbb + (long long)c * HW + k0 + hf * 32);
            uint4* dst = (uint4*)&Pcs[c][hf * 32];
            #pragma unroll
            for (int i = 0; i < 4; i++) dst[i] = src[i];
        }
        __syncthreads();
        s8v aS[4];
        #pragma unroll
        for (int ks = 0; ks < 4; ks++) aS[ks] = *(const s8v*)&Qks[w*16 + m][q*8 + ks*32];
        float mk[4], il[4];
        #pragma unroll
        for (int r = 0; r < 4; r++){
            int kg = k0 + w*16 + q*4 + r;
            mk[r] = mb[kg]; il[r] = 1.f / lb[kg];
        }
        #pragma unroll
        for (int ct = 0; ct < 4; ct++){
            f4v s = {0.f,0.f,0.f,0.f};
            #pragma unroll
            for (int ks = 0; ks < 4; ks++)
                s = __builtin_amdgcn_mfma_f32_16x16x32_bf16(aS[ks], bj[ct][ks], s, 0, 0, 0);
            s4v e4;
            #pragma unroll
            for (int r = 0; r < 4; r++)
                e4[r] = (short)f2bf(__expf(s[r]*scale - mk[r]) * il[r]);
            *(s4v*)&Et[ct*16 + m][w*16 + q*4] = e4;   // E^T[j][k], 4 consecutive k
        }
        __syncthreads();
        s8v aP[2][2];
        #pragma unroll
        for (int mt = 0; mt < 2; mt++)
            #pragma unroll
            for (int ks2 = 0; ks2 < 2; ks2++)
                aP[mt][ks2] = *(const s8v*)&Pcs[w*32 + mt*16 + m][q*8 + ks2*32];
        #pragma unroll
        for (int ct = 0; ct < 4; ct++){
            s8v bE0 = *(const s8v*)&Et[ct*16 + m][q*8];
            s8v bE1 = *(const s8v*)&Et[ct*16 + m][q*8 + 32];
            #pragma unroll
            for (int mt = 0; mt < 2; mt++){
                accL[mt][ct] = __builtin_amdgcn_mfma_f32_16x16x32_bf16(aP[mt][0], bE0, accL[mt][ct], 0, 0, 0);
                accL[mt][ct] = __builtin_amdgcn_mfma_f32_16x16x32_bf16(aP[mt][1], bE1, accL[mt][ct], 0, 0, 0);
            }
        }
    }
    #pragma unroll
    for (int mt = 0; mt < 2; mt++)
        #pragma unroll
        for (int ct = 0; ct < 4; ct++)
            #pragma unroll
            for (int r = 0; r < 4; r++){
                int c = w*32 + mt*16 + q*4 + r;
                long long idx = (long long)b*CO*HW + (long long)c*HW + j0 + ct*16 + m;
                O[idx] = accL[mt][ct][r] + xa[idx];
            }
}

extern "C" void kernel_launch(void* const* d_in, const int* in_sizes, int n_in,
                              void* d_out, int out_size, void* d_ws, size_t ws_size,
                              hipStream_t stream) {
    const float* x       = (const float*)d_in[0];
    const float* conv1_w = (const float*)d_in[1];
    const float* conv1_b = (const float*)d_in[2];
    const float* conv2_w = (const float*)d_in[3];
    const float* conv2_b = (const float*)d_in[4];
    const float* cw_w1   = (const float*)d_in[5];
    const float* cw_b1   = (const float*)d_in[6];
    const float* cw_g    = (const float*)d_in[7];
    const float* cw_bt   = (const float*)d_in[8];
    const float* cw_w2   = (const float*)d_in[9];
    const float* cw_b2   = (const float*)d_in[10];
    const float* a0_w    = (const float*)d_in[11];
    const float* a0_g    = (const float*)d_in[12];
    const float* a0_b    = (const float*)d_in[13];
    const float* a1_w    = (const float*)d_in[14];
    const float* a1_g    = (const float*)d_in[15];
    const float* a1_b    = (const float*)d_in[16];
    const float* a2_w    = (const float*)d_in[17];
    const float* a2_g    = (const float*)d_in[18];
    const float* a2_b    = (const float*)d_in[19];
    const float* a3_w    = (const float*)d_in[20];
    const float* a3_g    = (const float*)d_in[21];
    const float* a3_b    = (const float*)d_in[22];
    const float* ap_w    = (const float*)d_in[23];
    const float* ap_g    = (const float*)d_in[24];
    const float* ap_b    = (const float*)d_in[25];
    const float* pj_w    = (const float*)d_in[26];
    const float* pj_g    = (const float*)d_in[27];
    const float* pj_b    = (const float*)d_in[28];
    float* out = (float*)d_out;

    // workspace layout (floats); proj aliases xc; O + bf16 bufs alias cat region
    float* ws   = (float*)d_ws;
    float* avg  = ws;                 // 1024
    float* mx   = avg  + 1024;        // 1024
    float* sv   = mx   + 1024;        // 1024
    float* gp   = sv   + 1024;        // 1024
    float* bp   = gp   + 1024;        // 1024
    float* mrow = bp   + 1024;        // 16384
    float* lrow = mrow + 16384;       // 16384
    float* x1   = lrow + 16384;       // 4*128*4096 = 2,097,152
    float* xc   = x1   + 2097152;     // 4*256*4096 = 4,194,304
    float* cat  = xc   + 4194304;     // 4*1280*4096 = 20,971,520
    float* xa   = cat  + 20971520;    // 2,097,152   (end: ~112 MB)
    float* proj = xc;                 // alias: xc dead after conv branches
    float* Obuf = cat;                // alias: cat[0..2M) dead after proj GEMM
    unsigned short* P_bf  = (unsigned short*)(cat + 2097152);  // 2M bf16 each,
    unsigned short* PT_bf = P_bf  + 2097152;                   // inside dead cat region
    unsigned short* QT_bf = PT_bf + 2097152;

    const long long bsX  = (long long)CI * HW;    // 256*4096
    const long long bsXo = (long long)CO * HW;    // 128*4096
    const long long bsCat= 1280LL * HW;

    // 1. channel stats + channel weighting
    k_rowstats<<<dim3(NB*CI), 256, 0, stream>>>(x, avg, mx);
    k_cw<<<dim3(NB), 256, 0, stream>>>(avg, mx, cw_w1, cw_b1, cw_g, cw_bt, cw_w2, cw_b2, sv, gp);
    k_xc<<<dim3(4096), 256, 0, stream>>>(x, sv, xc);

    // 2. x1 = conv1(x) + b
    k_gemm<<<dim3(64, 2, NB), 256, 0, stream>>>(conv1_w, x, x1, conv1_b, 128, HW, 256, bsX, bsXo);

    // 3. ASPP branches into cat
    k_gemm <<<dim3(64, 4, NB), 256, 0, stream>>>(a0_w, xc, cat,              nullptr, 256, HW, 256, bsX, bsCat);
    k_conv3<<<dim3(64, 4, NB), 256, 0, stream>>>(a1_w, xc, cat + 256*HW,     3, bsX, bsCat);
    k_conv3<<<dim3(64, 4, NB), 256, 0, stream>>>(a2_w, xc, cat + 512*HW,     6, bsX, bsCat);
    k_conv3<<<dim3(64, 4, NB), 256, 0, stream>>>(a3_w, xc, cat + 768*HW,     9, bsX, bsCat);
    k_ln_gelu<<<dim3(16, NB), 256, 0, stream>>>(cat,            a0_g, a0_b, 256, bsCat, 1e-6f);
    k_ln_gelu<<<dim3(16, NB), 256, 0, stream>>>(cat + 256*HW,   a1_g, a1_b, 256, bsCat, 1e-6f);
    k_ln_gelu<<<dim3(16, NB), 256, 0, stream>>>(cat + 512*HW,   a2_g, a2_b, 256, bsCat, 1e-6f);
    k_ln_gelu<<<dim3(16, NB), 256, 0, stream>>>(cat + 768*HW,   a3_g, a3_b, 256, bsCat, 1e-6f);
    k_pool<<<dim3(NB), 256, 0, stream>>>(gp, ap_w, ap_g, ap_b, bp);
    k_bcast<<<dim3(4096), 256, 0, stream>>>(bp, cat);

    // 4. proj = GELU(LN(conv1x1(cat)))   (proj aliases xc)
    k_gemm<<<dim3(64, 4, NB), 256, 0, stream>>>(pj_w, cat, proj, nullptr, 256, HW, 1280, bsCat, bsX);
    k_ln_gelu<<<dim3(16, NB), 256, 0, stream>>>(proj, pj_g, pj_b, 256, bsX, 1e-6f);

    // 5. xa = conv1(proj) + b
    k_gemm<<<dim3(64, 2, NB), 256, 0, stream>>>(conv1_w, proj, xa, conv1_b, 128, HW, 256, bsX, bsXo);

    // 6. attention (bf16 MFMA, two-pass online softmax; O aliases cat)
    k_castT<<<dim3(64, 2, NB), 256, 0, stream>>>(x1, P_bf, PT_bf);
    k_castT<<<dim3(64, 2, NB), 256, 0, stream>>>(xa, nullptr, QT_bf);
    k_attn_stats_m<<<dim3(64, NB), 256, 0, stream>>>(QT_bf, PT_bf, mrow, lrow);
    k_attn_apply_m<<<dim3(64, NB), 256, 0, stream>>>(QT_bf, PT_bf, P_bf, mrow, lrow, xa, Obuf);

    // 7. out = conv2(O) + b
    k_gemm<<<dim3(64, 4, NB), 256, 0, stream>>>(conv2_w, Obuf, out, conv2_b, 256, HW, 128, bsXo, bsX);

    (void)in_sizes; (void)n_in; (void)out_size; (void)ws_size;
}

// Round 3
// 823.785 us; speedup vs baseline: 5.7863x; 3.1410x over previous
//
#include <hip/hip_runtime.h>
#include <hip/hip_bf16.h>
#include <math.h>

// Problem constants (B=4, Cin=256, Cout=128, H=W=64)
#define NB 4
#define CI 256
#define CO 128
#define HW 4096

typedef __attribute__((ext_vector_type(8))) short s8v;   // 8 bf16 = 4 VGPRs (MFMA A/B frag)
typedef __attribute__((ext_vector_type(4))) short s4v;
typedef __attribute__((ext_vector_type(4))) float f4v;   // MFMA C/D frag

__device__ __forceinline__ unsigned short f2bf(float f){
    __hip_bfloat16 h = __float2bfloat16(f);   // RNE
    return *reinterpret_cast<unsigned short*>(&h);
}

// exact-enough GELU: Abramowitz-Stegun 7.1.26 erf (max abs err 1.5e-7)
__device__ __forceinline__ float gelu_f(float x){
    float z  = x * 0.70710678118654752f;
    float az = fabsf(z);
    float tt = 1.f / (1.f + 0.3275911f * az);
    float poly = tt*(0.254829592f + tt*(-0.284496736f + tt*(1.421413741f +
                 tt*(-1.453152027f + tt*1.061405429f))));
    float erfv = 1.f - poly * __expf(-az*az);
    erfv = (z < 0.f) ? -erfv : erfv;
    return 0.5f * x * (1.f + erfv);
}

// ---------------- per-channel avg/max over HW ----------------
__global__ void k_rowstats(const float* __restrict__ x, float* __restrict__ avg, float* __restrict__ mx){
    int row = blockIdx.x;                 // b*256+c, 1024 rows
    const float* p = x + (long long)row * HW;
    int t = threadIdx.x;
    float s = 0.f, m = -1e30f;
    for (int i = t; i < HW; i += 256){ float v = p[i]; s += v; m = fmaxf(m, v); }
    __shared__ float ss[256], sm[256];
    ss[t] = s; sm[t] = m; __syncthreads();
    for (int o = 128; o > 0; o >>= 1){
        if (t < o){ ss[t] += ss[t+o]; sm[t] = fmaxf(sm[t], sm[t+o]); }
        __syncthreads();
    }
    if (t == 0){ avg[row] = ss[0] / (float)HW; mx[row] = sm[0]; }
}

// ---------------- ChannelWeighting; also gp = avg*(1+s) ----------------
__global__ void k_cw(const float* __restrict__ avg, const float* __restrict__ mx,
                     const float* __restrict__ w1, const float* __restrict__ b1,
                     const float* __restrict__ lng, const float* __restrict__ lnb,
                     const float* __restrict__ w2, const float* __restrict__ b2,
                     float* __restrict__ sv, float* __restrict__ gp){
    int b = blockIdx.x, t = threadIdx.x;  // 4 blocks x 256
    __shared__ float o_s[256];
    __shared__ float h_s[128];
    __shared__ float stat[2];
    float a = avg[b*256 + t];
    o_s[t] = fabsf(a - mx[b*256 + t]) * a;
    __syncthreads();
    if (t < 128){
        float h = b1[t];
        for (int i = 0; i < 256; i++) h += o_s[i] * w1[t*256 + i];
        h_s[t] = h;
    }
    __syncthreads();
    if (t == 0){
        float s = 0.f, s2 = 0.f;
        for (int j = 0; j < 128; j++){ s += h_s[j]; s2 += h_s[j]*h_s[j]; }
        float mean = s / 128.f;
        float var  = s2 / 128.f - mean*mean;
        stat[0] = mean; stat[1] = rsqrtf(var + 1e-5f);   // nn.LayerNorm eps
    }
    __syncthreads();
    if (t < 128) h_s[t] = lng[t] * ((h_s[t] - stat[0]) * stat[1]) + lnb[t];
    __syncthreads();
    float z = b2[t];
    for (int j = 0; j < 128; j++) z += h_s[j] * w2[t*128 + j];
    float sig = 1.f / (1.f + __expf(-z));
    sv[b*256 + t] = sig;
    gp[b*256 + t] = a * (1.f + sig);      // mean(xc) = mean(x)*(1+s)
}

// ---------------- weight casts ----------------
__global__ void k_wcast(const float* __restrict__ in, unsigned short* __restrict__ out){
    int i = blockIdx.x*256 + threadIdx.x;
    out[i] = f2bf(in[i]);
}
// conv3 weights [O=256][I=256][9] f32 -> [tap][O][I] bf16
__global__ void k_w3(const float* __restrict__ in, unsigned short* __restrict__ out){
    int j = blockIdx.x*256 + threadIdx.x;          // < 589824
    int tap = j >> 16, rem = j & 65535, o = rem >> 8, ci = rem & 255;
    out[j] = f2bf(in[o*2304 + ci*9 + tap]);
}

// ---------------- x -> xT bf16 [b][HW][256] and xcT = bf16(x*(1+s)) ----------------
__global__ void k_xT(const float* __restrict__ x, const float* __restrict__ sv,
                     unsigned short* __restrict__ xT, unsigned short* __restrict__ xcT){
    int b = blockIdx.z, c0 = blockIdx.y*64, h0 = blockIdx.x*64;
    __shared__ unsigned short T1[64][66], T2[64][66];
    int t = threadIdx.x;
    int hl = t & 63, cs = t >> 6;
    #pragma unroll
    for (int r = 0; r < 16; r++){
        int c = cs*16 + r;
        float v = x[((long long)b*256 + c0 + c)*HW + h0 + hl];
        float sc = 1.f + sv[b*256 + c0 + c];
        T1[c][hl] = f2bf(v);
        T2[c][hl] = f2bf(v*sc);
    }
    __syncthreads();
    int cl = t & 63, hs = t >> 6;
    #pragma unroll
    for (int r = 0; r < 16; r++){
        int h = hs*16 + r;
        long long o = ((long long)b*HW + h0 + h)*256 + c0 + cl;
        xT[o]  = T1[cl][h];
        xcT[o] = T2[cl][h];
    }
}

// ============ shared epilogue: LN(256ch)+GELU -> transposed bf16 ============
// acc[4][4]: value (ms,ct,r) at p=ct*16+m, c=w*64+ms*16+q*4+r
__device__ __forceinline__ void ln_epilogue(f4v acc[4][4],
        int b, int n0, int w, int lane, int m, int q,
        const float* Gs, const float* Bts,
        float Psum[4][64], float Psq[4][64], float Mn[64], float Iv[64],
        unsigned short* __restrict__ outT, int outPitch, int colOff){
    float ls[4], ls2[4];
    #pragma unroll
    for (int ct = 0; ct < 4; ct++){
        float s = 0.f, s2 = 0.f;
        #pragma unroll
        for (int ms = 0; ms < 4; ms++)
            #pragma unroll
            for (int r = 0; r < 4; r++){ float v = acc[ms][ct][r]; s += v; s2 += v*v; }
        ls[ct] = s; ls2[ct] = s2;
    }
    #pragma unroll
    for (int ct = 0; ct < 4; ct++){
        ls[ct]  += __shfl_xor(ls[ct], 16);  ls[ct]  += __shfl_xor(ls[ct], 32);
        ls2[ct] += __shfl_xor(ls2[ct], 16); ls2[ct] += __shfl_xor(ls2[ct], 32);
    }
    if (lane < 16){
        #pragma unroll
        for (int ct = 0; ct < 4; ct++){ Psum[w][ct*16+lane] = ls[ct]; Psq[w][ct*16+lane] = ls2[ct]; }
    }
    __syncthreads();
    int t = w*64 + lane;
    if (t < 64){
        float s  = Psum[0][t]+Psum[1][t]+Psum[2][t]+Psum[3][t];
        float s2 = Psq[0][t]+Psq[1][t]+Psq[2][t]+Psq[3][t];
        float mean = s * (1.f/256.f);
        Mn[t] = mean;
        Iv[t] = rsqrtf(s2*(1.f/256.f) - mean*mean + 1e-6f);
    }
    __syncthreads();
    #pragma unroll
    for (int ct = 0; ct < 4; ct++){
        int p = ct*16 + m;
        float mean = Mn[p], inv = Iv[p];
        long long rowb = ((long long)b*HW + n0 + p)*outPitch + colOff + w*64;
        #pragma unroll
        for (int ms = 0; ms < 4; ms++){
            s4v o4;
            #pragma unroll
            for (int r = 0; r < 4; r++){
                int c = w*64 + ms*16 + q*4 + r;
                float h = Gs[c]*((acc[ms][ct][r] - mean)*inv) + Bts[c];
                o4[r] = (short)f2bf(gelu_f(h));
            }
            *(s4v*)(outT + rowb + ms*16 + q*4) = o4;
        }
    }
}

// ---------------- fused 1x1-conv (MFMA) + LN + GELU -> transposed bf16 ----------------
// C[256][64pos] = A[256][K] @ BT[pos][K]^T ; LN over 256 ch; out bf16 [p][outPitch]+colOff
__global__ void k_branch1(const unsigned short* __restrict__ A, int K,
                          const unsigned short* __restrict__ BT,
                          const float* __restrict__ g, const float* __restrict__ beta,
                          unsigned short* __restrict__ outT, int outPitch, int colOff){
    int b = blockIdx.y, n0 = blockIdx.x*64;
    const unsigned short* BTb = BT + (long long)b*HW*K;
    __shared__ unsigned short As[256][40];
    __shared__ unsigned short Bs[64][40];
    __shared__ float Psum[4][64], Psq[4][64], Mn[64], Iv[64];
    __shared__ float Gs[256], Bts[256];
    int t = threadIdx.x, w = t>>6, lane = t&63, m = lane&15, q = lane>>4;
    Gs[t] = g[t]; Bts[t] = beta[t];
    f4v acc[4][4];
    #pragma unroll
    for (int ms = 0; ms < 4; ms++)
        #pragma unroll
        for (int ct = 0; ct < 4; ct++){ f4v z = {0.f,0.f,0.f,0.f}; acc[ms][ct] = z; }
    for (int k0 = 0; k0 < K; k0 += 32){
        __syncthreads();
        {   const uint4* src = (const uint4*)(A + (long long)t*K + k0);
            uint4* dst = (uint4*)&As[t][0];
            dst[0]=src[0]; dst[1]=src[1]; dst[2]=src[2]; dst[3]=src[3];
        }
        {   int n = t>>2, ch = t&3;
            *(uint4*)&Bs[n][ch*8] = *(const uint4*)(BTb + (long long)(n0+n)*K + k0 + ch*8);
        }
        __syncthreads();
        s8v bfr[4];
        #pragma unroll
        for (int ct = 0; ct < 4; ct++) bfr[ct] = *(const s8v*)&Bs[ct*16+m][q*8];
        #pragma unroll
        for (int ms = 0; ms < 4; ms++){
            s8v afr = *(const s8v*)&As[w*64 + ms*16 + m][q*8];
            #pragma unroll
            for (int ct = 0; ct < 4; ct++)
                acc[ms][ct] = __builtin_amdgcn_mfma_f32_16x16x32_bf16(afr, bfr[ct], acc[ms][ct], 0,0,0);
        }
    }
    __syncthreads();
    ln_epilogue(acc, b, n0, w, lane, m, q, Gs, Bts, Psum, Psq, Mn, Iv, outT, outPitch, colOff);
}

// ---------------- fused 3x3 dilated conv (MFMA) + LN + GELU -> catT bf16 ----------------
// Wb[tap][256][256] bf16; BT = xcT [b][HW][256]
__global__ void k_branch3(const unsigned short* __restrict__ Wb,
                          const unsigned short* __restrict__ BT, int d,
                          const float* __restrict__ g, const float* __restrict__ beta,
                          unsigned short* __restrict__ outT, int colOff){
    int b = blockIdx.y, y = blockIdx.x, n0 = y*64;
    const unsigned short* BTb = BT + (long long)b*HW*256;
    __shared__ unsigned short As[256][40];
    __shared__ unsigned short Bs[64][40];
    __shared__ float Psum[4][64], Psq[4][64], Mn[64], Iv[64];
    __shared__ float Gs[256], Bts[256];
    int t = threadIdx.x, w = t>>6, lane = t&63, m = lane&15, q = lane>>4;
    Gs[t] = g[t]; Bts[t] = beta[t];
    f4v acc[4][4];
    #pragma unroll
    for (int ms = 0; ms < 4; ms++)
        #pragma unroll
        for (int ct = 0; ct < 4; ct++){ f4v z = {0.f,0.f,0.f,0.f}; acc[ms][ct] = z; }
    for (int tap = 0; tap < 9; tap++){
        int dy = tap/3 - 1, dx = tap%3 - 1;
        int ys = y + dy*d;
        bool yok = (unsigned)ys < 64u;
        const unsigned short* wtap = Wb + (long long)tap*65536;
        for (int kc = 0; kc < 8; kc++){
            int ci0 = kc*32;
            __syncthreads();
            {   const uint4* src = (const uint4*)(wtap + (long long)t*256 + ci0);
                uint4* dst = (uint4*)&As[t][0];
                dst[0]=src[0]; dst[1]=src[1]; dst[2]=src[2]; dst[3]=src[3];
            }
            {   int n = t>>2, ch = t&3;
                int xs = n + dx*d;
                uint4 v = {0u,0u,0u,0u};
                if (yok && (unsigned)xs < 64u)
                    v = *(const uint4*)(BTb + (long long)(ys*64+xs)*256 + ci0 + ch*8);
                *(uint4*)&Bs[n][ch*8] = v;
            }
            __syncthreads();
            s8v bfr[4];
            #pragma unroll
            for (int ct = 0; ct < 4; ct++) bfr[ct] = *(const s8v*)&Bs[ct*16+m][q*8];
            #pragma unroll
            for (int ms = 0; ms < 4; ms++){
                s8v afr = *(const s8v*)&As[w*64 + ms*16 + m][q*8];
                #pragma unroll
                for (int ct = 0; ct < 4; ct++)
                    acc[ms][ct] = __builtin_amdgcn_mfma_f32_16x16x32_bf16(afr, bfr[ct], acc[ms][ct], 0,0,0);
            }
        }
    }
    __syncthreads();
    ln_epilogue(acc, b, n0, w, lane, m, q, Gs, Bts, Psum, Psq, Mn, Iv, outT, 1280, colOff);
}

// ---------------- conv1 (M=128) MFMA: P-mode (P_bf + PT_bf) or Q-mode (xa f32 + QT_bf) ----------------
__global__ void k_conv1m(const unsigned short* __restrict__ A,      // [128][256] bf16
                         const unsigned short* __restrict__ BT,     // [b][HW][256] bf16
                         const float* __restrict__ bias,
                         unsigned short* __restrict__ outT,         // [b][HW][128] bf16
                         unsigned short* __restrict__ outC,         // [b][128][HW] bf16 or null
                         float* __restrict__ outF){                 // [b][128][HW] f32 or null
    int b = blockIdx.y, n0 = blockIdx.x*64;
    const unsigned short* BTb = BT + (long long)b*HW*256;
    __shared__ unsigned short As[128][40];
    __shared__ unsigned short Bs[64][40];
    int t = threadIdx.x, w = t>>6, lane = t&63, m = lane&15, q = lane>>4;
    f4v acc[2][4];
    #pragma unroll
    for (int ms = 0; ms < 2; ms++)
        #pragma unroll
        for (int ct = 0; ct < 4; ct++){ f4v z = {0.f,0.f,0.f,0.f}; acc[ms][ct] = z; }
    for (int k0 = 0; k0 < 256; k0 += 32){
        __syncthreads();
        {   int r = t>>1, half = t&1;
            const uint4* src = (const uint4*)(A + (long long)r*256 + k0 + half*16);
            uint4* dst = (uint4*)&As[r][half*16];
            dst[0]=src[0]; dst[1]=src[1];
        }
        {   int n = t>>2, ch = t&3;
            *(uint4*)&Bs[n][ch*8] = *(const uint4*)(BTb + (long long)(n0+n)*256 + k0 + ch*8);
        }
        __syncthreads();
        s8v bfr[4];
        #pragma unroll
        for (int ct = 0; ct < 4; ct++) bfr[ct] = *(const s8v*)&Bs[ct*16+m][q*8];
        #pragma unroll
        for (int ms = 0; ms < 2; ms++){
            s8v afr = *(const s8v*)&As[w*32 + ms*16 + m][q*8];
            #pragma unroll
            for (int ct = 0; ct < 4; ct++)
                acc[ms][ct] = __builtin_amdgcn_mfma_f32_16x16x32_bf16(afr, bfr[ct], acc[ms][ct], 0,0,0);
        }
    }
    #pragma unroll
    for (int ct = 0; ct < 4; ct++){
        int p = n0 + ct*16 + m;
        #pragma unroll
        for (int ms = 0; ms < 2; ms++){
            s4v o4;
            float vals[4];
            #pragma unroll
            for (int r = 0; r < 4; r++){
                int c = w*32 + ms*16 + q*4 + r;
                vals[r] = acc[ms][ct][r] + bias[c];
                o4[r] = (short)f2bf(vals[r]);
            }
            *(s4v*)(outT + ((long long)b*HW + p)*128 + w*32 + ms*16 + q*4) = o4;
            if (outC){
                #pragma unroll
                for (int r = 0; r < 4; r++){
                    int c = w*32 + ms*16 + q*4 + r;
                    outC[((long long)b*128 + c)*HW + p] = (unsigned short)o4[r];
                }
            }
            if (outF){
                #pragma unroll
                for (int r = 0; r < 4; r++){
                    int c = w*32 + ms*16 + q*4 + r;
                    outF[((long long)b*128 + c)*HW + p] = vals[r];
                }
            }
        }
    }
}

// ---------------- conv2 (M=256, K=128) MFMA -> out f32 + bias ----------------
__global__ void k_gemm_out(const unsigned short* __restrict__ A,    // [256][128] bf16
                           const unsigned short* __restrict__ BT,   // [b][HW][128] bf16
                           const float* __restrict__ bias,
                           float* __restrict__ out){
    int b = blockIdx.y, n0 = blockIdx.x*64;
    const unsigned short* BTb = BT + (long long)b*HW*128;
    __shared__ unsigned short As[256][40];
    __shared__ unsigned short Bs[64][40];
    int t = threadIdx.x, w = t>>6, lane = t&63, m = lane&15, q = lane>>4;
    f4v acc[4][4];
    #pragma unroll
    for (int ms = 0; ms < 4; ms++)
        #pragma unroll
        for (int ct = 0; ct < 4; ct++){ f4v z = {0.f,0.f,0.f,0.f}; acc[ms][ct] = z; }
    for (int k0 = 0; k0 < 128; k0 += 32){
        __syncthreads();
        {   const uint4* src = (const uint4*)(A + (long long)t*128 + k0);
            uint4* dst = (uint4*)&As[t][0];
            dst[0]=src[0]; dst[1]=src[1]; dst[2]=src[2]; dst[3]=src[3];
        }
        {   int n = t>>2, ch = t&3;
            *(uint4*)&Bs[n][ch*8] = *(const uint4*)(BTb + (long long)(n0+n)*128 + k0 + ch*8);
        }
        __syncthreads();
        s8v bfr[4];
        #pragma unroll
        for (int ct = 0; ct < 4; ct++) bfr[ct] = *(const s8v*)&Bs[ct*16+m][q*8];
        #pragma unroll
        for (int ms = 0; ms < 4; ms++){
            s8v afr = *(const s8v*)&As[w*64 + ms*16 + m][q*8];
            #pragma unroll
            for (int ct = 0; ct < 4; ct++)
                acc[ms][ct] = __builtin_amdgcn_mfma_f32_16x16x32_bf16(afr, bfr[ct], acc[ms][ct], 0,0,0);
        }
    }
    #pragma unroll
    for (int ct = 0; ct < 4; ct++){
        int p = n0 + ct*16 + m;
        #pragma unroll
        for (int ms = 0; ms < 4; ms++)
            #pragma unroll
            for (int r = 0; r < 4; r++){
                int c = w*64 + ms*16 + q*4 + r;
                out[((long long)b*256 + c)*HW + p] = acc[ms][ct][r] + bias[c];
            }
    }
}

// ---------------- pooled branch: conv1x1(gp) -> LN -> GELU ----------------
__global__ void k_pool(const float* __restrict__ gp, const float* __restrict__ w,
                       const float* __restrict__ g, const float* __restrict__ bta,
                       float* __restrict__ bp){
    int b = blockIdx.x, t = threadIdx.x;   // 4 blocks x 256
    __shared__ float z_s[256];
    __shared__ float stat[2];
    float z = 0.f;
    for (int c = 0; c < 256; c++) z += gp[b*256 + c] * w[t*256 + c];
    z_s[t] = z;
    __syncthreads();
    if (t == 0){
        float s = 0.f, s2 = 0.f;
        for (int c = 0; c < 256; c++){ s += z_s[c]; s2 += z_s[c]*z_s[c]; }
        float mean = s / 256.f, var = s2 / 256.f - mean*mean;
        stat[0] = mean; stat[1] = rsqrtf(var + 1e-6f);
    }
    __syncthreads();
    float h = g[t] * ((z - stat[0]) * stat[1]) + bta[t];
    bp[b*256 + t] = gelu_f(h);
}

// ---------------- broadcast pooled branch into catT cols 1024..1279 ----------------
__global__ void k_bcastT(const float* __restrict__ bp, unsigned short* __restrict__ catT){
    int b = blockIdx.y;
    int i = blockIdx.x*256 + threadIdx.x;      // 131072 per batch
    int p = i >> 5, cj = (i & 31) * 8;
    s8v v8;
    #pragma unroll
    for (int k = 0; k < 8; k++) v8[k] = (short)f2bf(bp[b*256 + cj + k]);
    *(s8v*)(catT + ((long long)b*HW + p)*1280 + 1024 + cj) = v8;
}

// ---------------- cast f32 [CO][HW] -> bf16 transposed [HW][CO] ----------------
__global__ void k_castT(const float* __restrict__ X, unsigned short* __restrict__ Xbf,
                        unsigned short* __restrict__ XT){
    int b = blockIdx.z;
    int h0 = blockIdx.x * 64, c0 = blockIdx.y * 64;
    const float* Xb = X + ((long long)b*CO + c0) * HW + h0;
    __shared__ unsigned short T[64][66];
    int t = threadIdx.x;
    int hl = t & 63, cs = t >> 6;
    #pragma unroll
    for (int r = 0; r < 16; r++){
        int c = cs*16 + r;
        unsigned short v = f2bf(Xb[(long long)c*HW + hl]);
        T[c][hl] = v;
        if (Xbf) Xbf[((long long)b*CO + c0 + c)*HW + h0 + hl] = v;
    }
    __syncthreads();
    int cl = t & 63, hs = t >> 6;
    #pragma unroll
    for (int r = 0; r < 16; r++){
        int h = hs*16 + r;
        XT[((long long)b*HW + h0 + h)*CO + c0 + cl] = T[cl][h];
    }
}

// ---------------- attention pass 1 (MFMA bf16): per-row (m,l) over p ----------------
__global__ void k_attn_stats_m(const unsigned short* __restrict__ QT,
                               const unsigned short* __restrict__ PT,
                               float* __restrict__ mrow, float* __restrict__ lrow){
    int b = blockIdx.y, k0 = blockIdx.x * 64;
    const unsigned short* QTb = QT + (long long)b * HW * CO;
    const unsigned short* PTb = PT + (long long)b * HW * CO;
    __shared__ unsigned short Qs[64][136];
    __shared__ unsigned short Ps[64][136];
    int t = threadIdx.x;
    int w = t >> 6, lane = t & 63, m = lane & 15, q = lane >> 4;
    {
        int r = t >> 2, ch = t & 3;
        const uint4* src = (const uint4*)(QTb + (long long)(k0 + r) * CO + ch * 32);
        uint4* dst = (uint4*)&Qs[r][ch * 32];
        #pragma unroll
        for (int i = 0; i < 4; i++) dst[i] = src[i];
    }
    __syncthreads();
    s8v a[4];
    #pragma unroll
    for (int ks = 0; ks < 4; ks++) a[ks] = *(const s8v*)&Qs[w*16 + m][q*8 + ks*32];
    float rm[4], rl[4];
    #pragma unroll
    for (int r = 0; r < 4; r++){ rm[r] = -1e30f; rl[r] = 0.f; }
    const float scale = 0.015625f;           // 1/sqrt(4096)
    for (int j0 = 0; j0 < HW; j0 += 64){
        __syncthreads();
        {
            int r = t >> 2, ch = t & 3;
            const uint4* src = (const uint4*)(PTb + (long long)(j0 + r) * CO + ch * 32);
            uint4* dst = (uint4*)&Ps[r][ch * 32];
            #pragma unroll
            for (int i = 0; i < 4; i++) dst[i] = src[i];
        }
        __syncthreads();
        float sv[4][4];
        #pragma unroll
        for (int ct = 0; ct < 4; ct++){
            f4v acc = {0.f,0.f,0.f,0.f};
            #pragma unroll
            for (int ks = 0; ks < 4; ks++){
                s8v bv = *(const s8v*)&Ps[ct*16 + m][q*8 + ks*32];
                acc = __builtin_amdgcn_mfma_f32_16x16x32_bf16(a[ks], bv, acc, 0, 0, 0);
            }
            #pragma unroll
            for (int r = 0; r < 4; r++) sv[ct][r] = acc[r] * scale;
        }
        #pragma unroll
        for (int r = 0; r < 4; r++){
            float mx = fmaxf(fmaxf(sv[0][r], sv[1][r]), fmaxf(sv[2][r], sv[3][r]));
            #pragma unroll
            for (int msk = 1; msk < 16; msk <<= 1) mx = fmaxf(mx, __shfl_xor(mx, msk));
            float nm = fmaxf(rm[r], mx);
            float se = __expf(sv[0][r]-nm) + __expf(sv[1][r]-nm)
                     + __expf(sv[2][r]-nm) + __expf(sv[3][r]-nm);
            #pragma unroll
            for (int msk = 1; msk < 16; msk <<= 1) se += __shfl_xor(se, msk);
            rl[r] = rl[r] * __expf(rm[r] - nm) + se;
            rm[r] = nm;
        }
    }
    if (m == 0){
        #pragma unroll
        for (int r = 0; r < 4; r++){
            int k = k0 + w*16 + q*4 + r;
            mrow[(long long)b*HW + k] = rm[r];
            lrow[(long long)b*HW + k] = rl[r];
        }
    }
}

// ---------------- attention pass 2 (MFMA bf16): O = P @ A + xa ----------------
__global__ void k_attn_apply_m(const unsigned short* __restrict__ QT,
                               const unsigned short* __restrict__ PT,
                               const unsigned short* __restrict__ Pb,
                               const float* __restrict__ mrow, const float* __restrict__ lrow,
                               const float* __restrict__ xa, float* __restrict__ O){
    int b = blockIdx.y, j0 = blockIdx.x * 64;
    const unsigned short* QTb = QT + (long long)b * HW * CO;
    const unsigned short* PTb = PT + (long long)b * HW * CO;
    const unsigned short* Pbb = Pb + (long long)b * CO * HW;
    const float* mb = mrow + (long long)b * HW;
    const float* lb = lrow + (long long)b * HW;
    __shared__ unsigned short Pjs[64][136];
    __shared__ unsigned short Qks[64][136];
    __shared__ unsigned short Pcs[128][72];
    __shared__ unsigned short Et[64][72];
    int t = threadIdx.x;
    int w = t >> 6, lane = t & 63, m = lane & 15, q = lane >> 4;
    {
        int r = t >> 2, ch = t & 3;
        const uint4* src = (const uint4*)(PTb + (long long)(j0 + r) * CO + ch * 32);
        uint4* dst = (uint4*)&Pjs[r][ch * 32];
        #pragma unroll
        for (int i = 0; i < 4; i++) dst[i] = src[i];
    }
    __syncthreads();
    s8v bj[4][4];
    #pragma unroll
    for (int ct = 0; ct < 4; ct++)
        #pragma unroll
        for (int ks = 0; ks < 4; ks++)
            bj[ct][ks] = *(const s8v*)&Pjs[ct*16 + m][q*8 + ks*32];
    f4v accL[2][4];
    #pragma unroll
    for (int mt = 0; mt < 2; mt++)
        #pragma unroll
        for (int ct = 0; ct < 4; ct++){ f4v z = {0.f,0.f,0.f,0.f}; accL[mt][ct] = z; }
    const float scale = 0.015625f;
    for (int k0 = 0; k0 < HW; k0 += 64){
        __syncthreads();
        {
            int r = t >> 2, ch = t & 3;
            const uint4* src = (const uint4*)(QTb + (long long)(k0 + r) * CO + ch * 32);
            uint4* dst = (uint4*)&Qks[r][ch * 32];
            #pragma unroll
            for (int i = 0; i < 4; i++) dst[i] = src[i];
        }
        {
            int c = t >> 1, hf = t & 1;
            const uint4* src = (const uint4*)(Pbb + (long long)c * HW + k0 + hf * 32);
            uint4* dst = (uint4*)&Pcs[c][hf * 32];
            #pragma unroll
            for (int i = 0; i < 4; i++) dst[i] = src[i];
        }
        __syncthreads();
        s8v aS[4];
        #pragma unroll
        for (int ks = 0; ks < 4; ks++) aS[ks] = *(const s8v*)&Qks[w*16 + m][q*8 + ks*32];
        float mk[4], il[4];
        #pragma unroll
        for (int r = 0; r < 4; r++){
            int kg = k0 + w*16 + q*4 + r;
            mk[r] = mb[kg]; il[r] = 1.f / lb[kg];
        }
        #pragma unroll
        for (int ct = 0; ct < 4; ct++){
            f4v s = {0.f,0.f,0.f,0.f};
            #pragma unroll
            for (int ks = 0; ks < 4; ks++)
                s = __builtin_amdgcn_mfma_f32_16x16x32_bf16(aS[ks], bj[ct][ks], s, 0, 0, 0);
            s4v e4;
            #pragma unroll
            for (int r = 0; r < 4; r++)
                e4[r] = (short)f2bf(__expf(s[r]*scale - mk[r]) * il[r]);
            *(s4v*)&Et[ct*16 + m][w*16 + q*4] = e4;
        }
        __syncthreads();
        s8v aP[2][2];
        #pragma unroll
        for (int mt = 0; mt < 2; mt++)
            #pragma unroll
            for (int ks2 = 0; ks2 < 2; ks2++)
                aP[mt][ks2] = *(const s8v*)&Pcs[w*32 + mt*16 + m][q*8 + ks2*32];
        #pragma unroll
        for (int ct = 0; ct < 4; ct++){
            s8v bE0 = *(const s8v*)&Et[ct*16 + m][q*8];
            s8v bE1 = *(const s8v*)&Et[ct*16 + m][q*8 + 32];
            #pragma unroll
            for (int mt = 0; mt < 2; mt++){
                accL[mt][ct] = __builtin_amdgcn_mfma_f32_16x16x32_bf16(aP[mt][0], bE0, accL[mt][ct], 0, 0, 0);
                accL[mt][ct] = __builtin_amdgcn_mfma_f32_16x16x32_bf16(aP[mt][1], bE1, accL[mt][ct], 0, 0, 0);
            }
        }
    }
    #pragma unroll
    for (int mt = 0; mt < 2; mt++)
        #pragma unroll
        for (int ct = 0; ct < 4; ct++)
            #pragma unroll
            for (int r = 0; r < 4; r++){
                int c = w*32 + mt*16 + q*4 + r;
                long long idx = (long long)b*CO*HW + (long long)c*HW + j0 + ct*16 + m;
                O[idx] = accL[mt][ct][r] + xa[idx];
            }
}

extern "C" void kernel_launch(void* const* d_in, const int* in_sizes, int n_in,
                              void* d_out, int out_size, void* d_ws, size_t ws_size,
                              hipStream_t stream) {
    const float* x       = (const float*)d_in[0];
    const float* conv1_w = (const float*)d_in[1];
    const float* conv1_b = (const float*)d_in[2];
    const float* conv2_w = (const float*)d_in[3];
    const float* conv2_b = (const float*)d_in[4];
    const float* cw_w1   = (const float*)d_in[5];
    const float* cw_b1   = (const float*)d_in[6];
    const float* cw_g    = (const float*)d_in[7];
    const float* cw_bt   = (const float*)d_in[8];
    const float* cw_w2   = (const float*)d_in[9];
    const float* cw_b2   = (const float*)d_in[10];
    const float* a0_w    = (const float*)d_in[11];
    const float* a0_g    = (const float*)d_in[12];
    const float* a0_b    = (const float*)d_in[13];
    const float* a1_w    = (const float*)d_in[14];
    const float* a1_g    = (const float*)d_in[15];
    const float* a1_b    = (const float*)d_in[16];
    const float* a2_w    = (const float*)d_in[17];
    const float* a2_g    = (const float*)d_in[18];
    const float* a2_b    = (const float*)d_in[19];
    const float* a3_w    = (const float*)d_in[20];
    const float* a3_g    = (const float*)d_in[21];
    const float* a3_b    = (const float*)d_in[22];
    const float* ap_w    = (const float*)d_in[23];
    const float* ap_g    = (const float*)d_in[24];
    const float* ap_b    = (const float*)d_in[25];
    const float* pj_w    = (const float*)d_in[26];
    const float* pj_g    = (const float*)d_in[27];
    const float* pj_b    = (const float*)d_in[28];
    float* out = (float*)d_out;

    // ---- workspace layout ----
    float* ws   = (float*)d_ws;
    float* avg  = ws;                  // 1024
    float* mx   = ws + 1024;           // 1024
    float* sv   = ws + 2048;           // 1024
    float* gp   = ws + 3072;           // 1024
    float* bp   = ws + 4096;           // 1024
    float* mrow = ws + 5120;           // 16384
    float* lrow = ws + 21504;          // 16384
    float* xa   = ws + 37888;          // 2,097,152
    float* O    = xa + 2097152;        // 2,097,152
    unsigned short* sb = (unsigned short*)(ws + 4232192);
    unsigned short* xT    = sb;                    // 4,194,304
    unsigned short* xcT   = sb + 4194304;          // 4,194,304
    unsigned short* catT  = sb + 8388608;          // 20,971,520
    unsigned short* projT = sb + 29360128;         // 4,194,304
    unsigned short* P_bf  = sb + 33554432;         // 2,097,152
    unsigned short* PT_bf = sb + 35651584;         // 2,097,152
    unsigned short* QT_bf = sb + 37748736;         // 2,097,152
    unsigned short* OT_bf = sb + 39845888;         // 2,097,152
    unsigned short* w_c1  = sb + 41943040;         // 32768
    unsigned short* w_a0  = sb + 41975808;         // 65536
    unsigned short* w_pj  = sb + 42041344;         // 327680
    unsigned short* w_c2  = sb + 42369024;         // 32768
    unsigned short* w_d3  = sb + 42401792;         // 589824
    unsigned short* w_d6  = sb + 42991616;         // 589824
    unsigned short* w_d9  = sb + 43581440;         // 589824

    // ---- stats + channel weighting (f32, tiny) ----
    k_rowstats<<<dim3(NB*CI), 256, 0, stream>>>(x, avg, mx);
    k_cw<<<dim3(NB), 256, 0, stream>>>(avg, mx, cw_w1, cw_b1, cw_g, cw_bt, cw_w2, cw_b2, sv, gp);

    // ---- weight casts ----
    k_wcast<<<dim3(128),  256, 0, stream>>>(conv1_w, w_c1);
    k_wcast<<<dim3(256),  256, 0, stream>>>(a0_w,    w_a0);
    k_wcast<<<dim3(1280), 256, 0, stream>>>(pj_w,    w_pj);
    k_wcast<<<dim3(128),  256, 0, stream>>>(conv2_w, w_c2);
    k_w3<<<dim3(2304), 256, 0, stream>>>(a1_w, w_d3);
    k_w3<<<dim3(2304), 256, 0, stream>>>(a2_w, w_d6);
    k_w3<<<dim3(2304), 256, 0, stream>>>(a3_w, w_d9);

    // ---- x -> xT bf16 and xcT = bf16(x*(1+s)) ----
    k_xT<<<dim3(64, 4, NB), 256, 0, stream>>>(x, sv, xT, xcT);

    // ---- x1 = conv1(x)+b -> P_bf/PT_bf ----
    k_conv1m<<<dim3(64, NB), 256, 0, stream>>>(w_c1, xT, conv1_b, PT_bf, P_bf, nullptr);

    // ---- ASPP branches (fused conv+LN+GELU -> catT bf16) ----
    k_branch1<<<dim3(64, NB), 256, 0, stream>>>(w_a0, 256, xcT, a0_g, a0_b, catT, 1280, 0);
    k_branch3<<<dim3(64, NB), 256, 0, stream>>>(w_d3, xcT, 3, a1_g, a1_b, catT, 256);
    k_branch3<<<dim3(64, NB), 256, 0, stream>>>(w_d6, xcT, 6, a2_g, a2_b, catT, 512);
    k_branch3<<<dim3(64, NB), 256, 0, stream>>>(w_d9, xcT, 9, a3_g, a3_b, catT, 768);
    k_pool<<<dim3(NB), 256, 0, stream>>>(gp, ap_w, ap_g, ap_b, bp);
    k_bcastT<<<dim3(512, NB), 256, 0, stream>>>(bp, catT);

    // ---- proj = GELU(LN(conv1x1(cat))) -> projT bf16 ----
    k_branch1<<<dim3(64, NB), 256, 0, stream>>>(w_pj, 1280, catT, pj_g, pj_b, projT, 256, 0);

    // ---- xa = conv1(proj)+b -> xa f32 + QT_bf ----
    k_conv1m<<<dim3(64, NB), 256, 0, stream>>>(w_c1, projT, conv1_b, QT_bf, nullptr, xa);

    // ---- attention ----
    k_attn_stats_m<<<dim3(64, NB), 256, 0, stream>>>(QT_bf, PT_bf, mrow, lrow);
    k_attn_apply_m<<<dim3(64, NB), 256, 0, stream>>>(QT_bf, PT_bf, P_bf, mrow, lrow, xa, O);

    // ---- O -> OT bf16; out = conv2(O)+b ----
    k_castT<<<dim3(64, 2, NB), 256, 0, stream>>>(O, nullptr, OT_bf);
    k_gemm_out<<<dim3(64, NB), 256, 0, stream>>>(w_c2, OT_bf, conv2_b, out);

    (void)in_sizes; (void)n_in; (void)out_size; (void)ws_size;
}

// Round 4
// 576.329 us; speedup vs baseline: 8.2708x; 1.4294x over previous
//
#include <hip/hip_runtime.h>
#include <hip/hip_bf16.h>
#include <math.h>

// Problem constants (B=4, Cin=256, Cout=128, H=W=64)
#define NB 4
#define CI 256
#define CO 128
#define HW 4096

typedef __attribute__((ext_vector_type(8))) short s8v;   // 8 bf16 = 4 VGPRs (MFMA A/B frag)
typedef __attribute__((ext_vector_type(4))) short s4v;
typedef __attribute__((ext_vector_type(4))) float f4v;   // MFMA C/D frag

__device__ __forceinline__ unsigned short f2bf(float f){
    __hip_bfloat16 h = __float2bfloat16(f);   // RNE
    return *reinterpret_cast<unsigned short*>(&h);
}

// A&S 7.1.26 erf (max abs err 1.5e-7)
__device__ __forceinline__ float gelu_f(float x){
    float z  = x * 0.70710678118654752f;
    float az = fabsf(z);
    float tt = 1.f / (1.f + 0.3275911f * az);
    float poly = tt*(0.254829592f + tt*(-0.284496736f + tt*(1.421413741f +
                 tt*(-1.453152027f + tt*1.061405429f))));
    float erfv = 1.f - poly * __expf(-az*az);
    erfv = (z < 0.f) ? -erfv : erfv;
    return 0.5f * x * (1.f + erfv);
}

// ---------------- per-channel avg/max over HW ----------------
__global__ void k_rowstats(const float* __restrict__ x, float* __restrict__ avg, float* __restrict__ mx){
    int row = blockIdx.x;
    const float* p = x + (long long)row * HW;
    int t = threadIdx.x;
    float s = 0.f, m = -1e30f;
    for (int i = t; i < HW; i += 256){ float v = p[i]; s += v; m = fmaxf(m, v); }
    __shared__ float ss[256], sm[256];
    ss[t] = s; sm[t] = m; __syncthreads();
    for (int o = 128; o > 0; o >>= 1){
        if (t < o){ ss[t] += ss[t+o]; sm[t] = fmaxf(sm[t], sm[t+o]); }
        __syncthreads();
    }
    if (t == 0){ avg[row] = ss[0] / (float)HW; mx[row] = sm[0]; }
}

// ---------------- ChannelWeighting; also gp = avg*(1+s) ----------------
__global__ void k_cw(const float* __restrict__ avg, const float* __restrict__ mx,
                     const float* __restrict__ w1, const float* __restrict__ b1,
                     const float* __restrict__ lng, const float* __restrict__ lnb,
                     const float* __restrict__ w2, const float* __restrict__ b2,
                     float* __restrict__ sv, float* __restrict__ gp){
    int b = blockIdx.x, t = threadIdx.x;
    __shared__ float o_s[256];
    __shared__ float h_s[128];
    __shared__ float stat[2];
    float a = avg[b*256 + t];
    o_s[t] = fabsf(a - mx[b*256 + t]) * a;
    __syncthreads();
    if (t < 128){
        float h = b1[t];
        for (int i = 0; i < 256; i++) h += o_s[i] * w1[t*256 + i];
        h_s[t] = h;
    }
    __syncthreads();
    if (t == 0){
        float s = 0.f, s2 = 0.f;
        for (int j = 0; j < 128; j++){ s += h_s[j]; s2 += h_s[j]*h_s[j]; }
        float mean = s / 128.f;
        float var  = s2 / 128.f - mean*mean;
        stat[0] = mean; stat[1] = rsqrtf(var + 1e-5f);
    }
    __syncthreads();
    if (t < 128) h_s[t] = lng[t] * ((h_s[t] - stat[0]) * stat[1]) + lnb[t];
    __syncthreads();
    float z = b2[t];
    for (int j = 0; j < 128; j++) z += h_s[j] * w2[t*128 + j];
    float sig = 1.f / (1.f + __expf(-z));
    sv[b*256 + t] = sig;
    gp[b*256 + t] = a * (1.f + sig);
}

// ---------------- weight casts ----------------
__global__ void k_wcast(const float* __restrict__ in, unsigned short* __restrict__ out){
    int i = blockIdx.x*256 + threadIdx.x;
    out[i] = f2bf(in[i]);
}
// conv3 weights [O=256][I=256][9] f32 -> [tap][O][I] bf16
__global__ void k_w3(const float* __restrict__ in, unsigned short* __restrict__ out){
    int j = blockIdx.x*256 + threadIdx.x;
    int tap = j >> 16, rem = j & 65535, o = rem >> 8, ci = rem & 255;
    out[j] = f2bf(in[o*2304 + ci*9 + tap]);
}

// ---------------- x -> xT bf16 [b][HW][256] and xcT = bf16(x*(1+s)) ----------------
__global__ void k_xT(const float* __restrict__ x, const float* __restrict__ sv,
                     unsigned short* __restrict__ xT, unsigned short* __restrict__ xcT){
    int b = blockIdx.z, c0 = blockIdx.y*64, h0 = blockIdx.x*64;
    __shared__ unsigned short T1[64][66], T2[64][66];
    int t = threadIdx.x;
    int hl = t & 63, cs = t >> 6;
    #pragma unroll
    for (int r = 0; r < 16; r++){
        int c = cs*16 + r;
        float v = x[((long long)b*256 + c0 + c)*HW + h0 + hl];
        float sc = 1.f + sv[b*256 + c0 + c];
        T1[c][hl] = f2bf(v);
        T2[c][hl] = f2bf(v*sc);
    }
    __syncthreads();
    int cl = t & 63, hs = t >> 6;
    #pragma unroll
    for (int r = 0; r < 16; r++){
        int h = hs*16 + r;
        long long o = ((long long)b*HW + h0 + h)*256 + c0 + cl;
        xT[o]  = T1[cl][h];
        xcT[o] = T2[cl][h];
    }
}

// ============ 8-wave epilogue: LN(256ch)+GELU -> transposed bf16 ============
// acc[2][4]: (ms,ct,r) at p=ct*16+m, c=w*32+ms*16+q*4+r  (w=0..7)
__device__ __forceinline__ void ln_epi8(f4v acc[2][4],
        int b, int n0, int w, int lane, int m, int q, int t,
        const float* Gs, const float* Bts,
        float (*Psum)[64], float (*Psq)[64], float* Mn, float* Iv,
        unsigned short* __restrict__ outT, int outPitch, int colOff){
    float ls[4], ls2[4];
    #pragma unroll
    for (int ct = 0; ct < 4; ct++){
        float s = 0.f, s2 = 0.f;
        #pragma unroll
        for (int ms = 0; ms < 2; ms++)
            #pragma unroll
            for (int r = 0; r < 4; r++){ float v = acc[ms][ct][r]; s += v; s2 += v*v; }
        ls[ct] = s; ls2[ct] = s2;
    }
    #pragma unroll
    for (int ct = 0; ct < 4; ct++){
        ls[ct]  += __shfl_xor(ls[ct], 16);  ls[ct]  += __shfl_xor(ls[ct], 32);
        ls2[ct] += __shfl_xor(ls2[ct], 16); ls2[ct] += __shfl_xor(ls2[ct], 32);
    }
    if (lane < 16){
        #pragma unroll
        for (int ct = 0; ct < 4; ct++){ Psum[w][ct*16+lane] = ls[ct]; Psq[w][ct*16+lane] = ls2[ct]; }
    }
    __syncthreads();
    if (t < 64){
        float s = 0.f, s2 = 0.f;
        #pragma unroll
        for (int ww = 0; ww < 8; ww++){ s += Psum[ww][t]; s2 += Psq[ww][t]; }
        float mean = s * (1.f/256.f);
        Mn[t] = mean;
        Iv[t] = rsqrtf(s2*(1.f/256.f) - mean*mean + 1e-6f);
    }
    __syncthreads();
    #pragma unroll
    for (int ct = 0; ct < 4; ct++){
        int p = ct*16 + m;
        float mean = Mn[p], inv = Iv[p];
        long long rowb = ((long long)b*HW + n0 + p)*outPitch + colOff;
        #pragma unroll
        for (int ms = 0; ms < 2; ms++){
            s4v o4;
            #pragma unroll
            for (int r = 0; r < 4; r++){
                int c = w*32 + ms*16 + q*4 + r;
                float h = Gs[c]*((acc[ms][ct][r] - mean)*inv) + Bts[c];
                o4[r] = (short)f2bf(gelu_f(h));
            }
            *(s4v*)(outT + rowb + w*32 + ms*16 + q*4) = o4;
        }
    }
}

// ---------------- fused 1x1-conv (MFMA) + LN + GELU, 512 threads ----------------
__global__ __launch_bounds__(512)
void k_branch1(const unsigned short* __restrict__ A, int K,
               const unsigned short* __restrict__ BT,
               const float* __restrict__ g, const float* __restrict__ beta,
               unsigned short* __restrict__ outT, int outPitch, int colOff){
    int b = blockIdx.y, n0 = blockIdx.x*64;
    const unsigned short* BTb = BT + (long long)b*HW*K;
    __shared__ unsigned short As[256][40];
    __shared__ unsigned short Bs[64][40];
    __shared__ float Psum[8][64], Psq[8][64], Mn[64], Iv[64];
    __shared__ float Gs[256], Bts[256];
    int t = threadIdx.x, w = t>>6, lane = t&63, m = lane&15, q = lane>>4;
    if (t < 256){ Gs[t] = g[t]; Bts[t] = beta[t]; }
    f4v acc[2][4];
    #pragma unroll
    for (int ms = 0; ms < 2; ms++)
        #pragma unroll
        for (int ct = 0; ct < 4; ct++){ f4v z = {0.f,0.f,0.f,0.f}; acc[ms][ct] = z; }
    for (int k0 = 0; k0 < K; k0 += 32){
        __syncthreads();
        {   int r = t>>1, half = t&1;
            const uint4* src = (const uint4*)(A + (long long)r*K + k0 + half*16);
            uint4* dst = (uint4*)&As[r][half*16];
            dst[0]=src[0]; dst[1]=src[1];
        }
        {   int n = t>>3, ch = t&7;
            *(uint2*)&Bs[n][ch*4] = *(const uint2*)(BTb + (long long)(n0+n)*K + k0 + ch*4);
        }
        __syncthreads();
        s8v bfr[4];
        #pragma unroll
        for (int ct = 0; ct < 4; ct++) bfr[ct] = *(const s8v*)&Bs[ct*16+m][q*8];
        #pragma unroll
        for (int ms = 0; ms < 2; ms++){
            s8v afr = *(const s8v*)&As[w*32 + ms*16 + m][q*8];
            #pragma unroll
            for (int ct = 0; ct < 4; ct++)
                acc[ms][ct] = __builtin_amdgcn_mfma_f32_16x16x32_bf16(afr, bfr[ct], acc[ms][ct], 0,0,0);
        }
    }
    __syncthreads();
    ln_epi8(acc, b, n0, w, lane, m, q, t, Gs, Bts, Psum, Psq, Mn, Iv, outT, outPitch, colOff);
}

// ---------------- fused 3x3 dilated conv (MFMA) + LN + GELU, 512 threads ----------------
__global__ __launch_bounds__(512)
void k_branch3(const unsigned short* __restrict__ Wb,
               const unsigned short* __restrict__ BT, int d,
               const float* __restrict__ g, const float* __restrict__ beta,
               unsigned short* __restrict__ outT, int colOff){
    int b = blockIdx.y, y = blockIdx.x, n0 = y*64;
    const unsigned short* BTb = BT + (long long)b*HW*256;
    __shared__ unsigned short As[256][40];
    __shared__ unsigned short Bs[64][40];
    __shared__ float Psum[8][64], Psq[8][64], Mn[64], Iv[64];
    __shared__ float Gs[256], Bts[256];
    int t = threadIdx.x, w = t>>6, lane = t&63, m = lane&15, q = lane>>4;
    if (t < 256){ Gs[t] = g[t]; Bts[t] = beta[t]; }
    f4v acc[2][4];
    #pragma unroll
    for (int ms = 0; ms < 2; ms++)
        #pragma unroll
        for (int ct = 0; ct < 4; ct++){ f4v z = {0.f,0.f,0.f,0.f}; acc[ms][ct] = z; }
    for (int tap = 0; tap < 9; tap++){
        int dy = tap/3 - 1, dx = tap%3 - 1;
        int ys = y + dy*d;
        bool yok = (unsigned)ys < 64u;
        const unsigned short* wtap = Wb + (long long)tap*65536;
        for (int kc = 0; kc < 8; kc++){
            int ci0 = kc*32;
            __syncthreads();
            {   int r = t>>1, half = t&1;
                const uint4* src = (const uint4*)(wtap + (long long)r*256 + ci0 + half*16);
                uint4* dst = (uint4*)&As[r][half*16];
                dst[0]=src[0]; dst[1]=src[1];
            }
            {   int n = t>>3, ch = t&7;
                int xs = n + dx*d;
                uint2 v = {0u,0u};
                if (yok && (unsigned)xs < 64u)
                    v = *(const uint2*)(BTb + (long long)(ys*64+xs)*256 + ci0 + ch*4);
                *(uint2*)&Bs[n][ch*4] = v;
            }
            __syncthreads();
            s8v bfr[4];
            #pragma unroll
            for (int ct = 0; ct < 4; ct++) bfr[ct] = *(const s8v*)&Bs[ct*16+m][q*8];
            #pragma unroll
            for (int ms = 0; ms < 2; ms++){
                s8v afr = *(const s8v*)&As[w*32 + ms*16 + m][q*8];
                #pragma unroll
                for (int ct = 0; ct < 4; ct++)
                    acc[ms][ct] = __builtin_amdgcn_mfma_f32_16x16x32_bf16(afr, bfr[ct], acc[ms][ct], 0,0,0);
            }
        }
    }
    __syncthreads();
    ln_epi8(acc, b, n0, w, lane, m, q, t, Gs, Bts, Psum, Psq, Mn, Iv, outT, 1280, colOff);
}

// ---------------- conv1 (M=128) MFMA ----------------
__global__ __launch_bounds__(256)
void k_conv1m(const unsigned short* __restrict__ A,      // [128][256] bf16
              const unsigned short* __restrict__ BT,     // [b][HW][256] bf16
              const float* __restrict__ bias,
              unsigned short* __restrict__ outT,         // [b][HW][128] bf16
              unsigned short* __restrict__ outC,         // [b][128][HW] bf16 or null
              float* __restrict__ outF){                 // [b][128][HW] f32 or null
    int b = blockIdx.y, n0 = blockIdx.x*64;
    const unsigned short* BTb = BT + (long long)b*HW*256;
    __shared__ unsigned short As[128][40];
    __shared__ unsigned short Bs[64][40];
    int t = threadIdx.x, w = t>>6, lane = t&63, m = lane&15, q = lane>>4;
    f4v acc[2][4];
    #pragma unroll
    for (int ms = 0; ms < 2; ms++)
        #pragma unroll
        for (int ct = 0; ct < 4; ct++){ f4v z = {0.f,0.f,0.f,0.f}; acc[ms][ct] = z; }
    for (int k0 = 0; k0 < 256; k0 += 32){
        __syncthreads();
        {   int r = t>>1, half = t&1;
            const uint4* src = (const uint4*)(A + (long long)r*256 + k0 + half*16);
            uint4* dst = (uint4*)&As[r][half*16];
            dst[0]=src[0]; dst[1]=src[1];
        }
        {   int n = t>>2, ch = t&3;
            *(uint4*)&Bs[n][ch*8] = *(const uint4*)(BTb + (long long)(n0+n)*256 + k0 + ch*8);
        }
        __syncthreads();
        s8v bfr[4];
        #pragma unroll
        for (int ct = 0; ct < 4; ct++) bfr[ct] = *(const s8v*)&Bs[ct*16+m][q*8];
        #pragma unroll
        for (int ms = 0; ms < 2; ms++){
            s8v afr = *(const s8v*)&As[w*32 + ms*16 + m][q*8];
            #pragma unroll
            for (int ct = 0; ct < 4; ct++)
                acc[ms][ct] = __builtin_amdgcn_mfma_f32_16x16x32_bf16(afr, bfr[ct], acc[ms][ct], 0,0,0);
        }
    }
    #pragma unroll
    for (int ct = 0; ct < 4; ct++){
        int p = n0 + ct*16 + m;
        #pragma unroll
        for (int ms = 0; ms < 2; ms++){
            s4v o4;
            float vals[4];
            #pragma unroll
            for (int r = 0; r < 4; r++){
                int c = w*32 + ms*16 + q*4 + r;
                vals[r] = acc[ms][ct][r] + bias[c];
                o4[r] = (short)f2bf(vals[r]);
            }
            *(s4v*)(outT + ((long long)b*HW + p)*128 + w*32 + ms*16 + q*4) = o4;
            if (outC){
                #pragma unroll
                for (int r = 0; r < 4; r++){
                    int c = w*32 + ms*16 + q*4 + r;
                    outC[((long long)b*128 + c)*HW + p] = (unsigned short)o4[r];
                }
            }
            if (outF){
                #pragma unroll
                for (int r = 0; r < 4; r++){
                    int c = w*32 + ms*16 + q*4 + r;
                    outF[((long long)b*128 + c)*HW + p] = vals[r];
                }
            }
        }
    }
}

// ---------------- conv2 (M=256, K=128) MFMA -> out f32 + bias ----------------
__global__ __launch_bounds__(256)
void k_gemm_out(const unsigned short* __restrict__ A,    // [256][128] bf16
                const unsigned short* __restrict__ BT,   // [b][HW][128] bf16
                const float* __restrict__ bias,
                float* __restrict__ out){
    int b = blockIdx.y, n0 = blockIdx.x*64;
    const unsigned short* BTb = BT + (long long)b*HW*128;
    __shared__ unsigned short As[256][40];
    __shared__ unsigned short Bs[64][40];
    int t = threadIdx.x, w = t>>6, lane = t&63, m = lane&15, q = lane>>4;
    f4v acc[4][4];
    #pragma unroll
    for (int ms = 0; ms < 4; ms++)
        #pragma unroll
        for (int ct = 0; ct < 4; ct++){ f4v z = {0.f,0.f,0.f,0.f}; acc[ms][ct] = z; }
    for (int k0 = 0; k0 < 128; k0 += 32){
        __syncthreads();
        {   const uint4* src = (const uint4*)(A + (long long)t*128 + k0);
            uint4* dst = (uint4*)&As[t][0];
            dst[0]=src[0]; dst[1]=src[1]; dst[2]=src[2]; dst[3]=src[3];
        }
        {   int n = t>>2, ch = t&3;
            *(uint4*)&Bs[n][ch*8] = *(const uint4*)(BTb + (long long)(n0+n)*128 + k0 + ch*8);
        }
        __syncthreads();
        s8v bfr[4];
        #pragma unroll
        for (int ct = 0; ct < 4; ct++) bfr[ct] = *(const s8v*)&Bs[ct*16+m][q*8];
        #pragma unroll
        for (int ms = 0; ms < 4; ms++){
            s8v afr = *(const s8v*)&As[w*64 + ms*16 + m][q*8];
            #pragma unroll
            for (int ct = 0; ct < 4; ct++)
                acc[ms][ct] = __builtin_amdgcn_mfma_f32_16x16x32_bf16(afr, bfr[ct], acc[ms][ct], 0,0,0);
        }
    }
    #pragma unroll
    for (int ct = 0; ct < 4; ct++){
        int p = n0 + ct*16 + m;
        #pragma unroll
        for (int ms = 0; ms < 4; ms++)
            #pragma unroll
            for (int r = 0; r < 4; r++){
                int c = w*64 + ms*16 + q*4 + r;
                out[((long long)b*256 + c)*HW + p] = acc[ms][ct][r] + bias[c];
            }
    }
}

// ---------------- pooled branch ----------------
__global__ void k_pool(const float* __restrict__ gp, const float* __restrict__ w,
                       const float* __restrict__ g, const float* __restrict__ bta,
                       float* __restrict__ bp){
    int b = blockIdx.x, t = threadIdx.x;
    __shared__ float z_s[256];
    __shared__ float stat[2];
    float z = 0.f;
    for (int c = 0; c < 256; c++) z += gp[b*256 + c] * w[t*256 + c];
    z_s[t] = z;
    __syncthreads();
    if (t == 0){
        float s = 0.f, s2 = 0.f;
        for (int c = 0; c < 256; c++){ s += z_s[c]; s2 += z_s[c]*z_s[c]; }
        float mean = s / 256.f, var = s2 / 256.f - mean*mean;
        stat[0] = mean; stat[1] = rsqrtf(var + 1e-6f);
    }
    __syncthreads();
    float h = g[t] * ((z - stat[0]) * stat[1]) + bta[t];
    bp[b*256 + t] = gelu_f(h);
}

// ---------------- broadcast pooled branch into catT cols 1024..1279 ----------------
__global__ void k_bcastT(const float* __restrict__ bp, unsigned short* __restrict__ catT){
    int b = blockIdx.y;
    int i = blockIdx.x*256 + threadIdx.x;
    int p = i >> 5, cj = (i & 31) * 8;
    s8v v8;
    #pragma unroll
    for (int k = 0; k < 8; k++) v8[k] = (short)f2bf(bp[b*256 + cj + k]);
    *(s8v*)(catT + ((long long)b*HW + p)*1280 + 1024 + cj) = v8;
}

// ---------------- attention pass 1 (split-j): partial (m,l) ----------------
__global__ __launch_bounds__(256)
void k_attn_stats2(const unsigned short* __restrict__ QT,
                   const unsigned short* __restrict__ PT,
                   float* __restrict__ mpart, float* __restrict__ lpart){
    int b = blockIdx.z, jc = blockIdx.y, k0 = blockIdx.x * 64;
    const unsigned short* QTb = QT + (long long)b * HW * CO;
    const unsigned short* PTb = PT + (long long)b * HW * CO;
    __shared__ unsigned short Qs[64][136];
    __shared__ unsigned short Ps[64][136];
    int t = threadIdx.x;
    int w = t >> 6, lane = t & 63, m = lane & 15, q = lane >> 4;
    {
        int r = t >> 2, ch = t & 3;
        const uint4* src = (const uint4*)(QTb + (long long)(k0 + r) * CO + ch * 32);
        uint4* dst = (uint4*)&Qs[r][ch * 32];
        #pragma unroll
        for (int i = 0; i < 4; i++) dst[i] = src[i];
    }
    __syncthreads();
    s8v a[4];
    #pragma unroll
    for (int ks = 0; ks < 4; ks++) a[ks] = *(const s8v*)&Qs[w*16 + m][q*8 + ks*32];
    float rm[4], rl[4];
    #pragma unroll
    for (int r = 0; r < 4; r++){ rm[r] = -1e30f; rl[r] = 0.f; }
    const float scale = 0.015625f;           // 1/sqrt(4096)
    int jbase = jc * 1024;
    for (int jt = 0; jt < 16; jt++){
        int j0 = jbase + jt*64;
        __syncthreads();
        {
            int r = t >> 2, ch = t & 3;
            const uint4* src = (const uint4*)(PTb + (long long)(j0 + r) * CO + ch * 32);
            uint4* dst = (uint4*)&Ps[r][ch * 32];
            #pragma unroll
            for (int i = 0; i < 4; i++) dst[i] = src[i];
        }
        __syncthreads();
        float sv[4][4];
        #pragma unroll
        for (int ct = 0; ct < 4; ct++){
            f4v acc = {0.f,0.f,0.f,0.f};
            #pragma unroll
            for (int ks = 0; ks < 4; ks++){
                s8v bv = *(const s8v*)&Ps[ct*16 + m][q*8 + ks*32];
                acc = __builtin_amdgcn_mfma_f32_16x16x32_bf16(a[ks], bv, acc, 0, 0, 0);
            }
            #pragma unroll
            for (int r = 0; r < 4; r++) sv[ct][r] = acc[r] * scale;
        }
        #pragma unroll
        for (int r = 0; r < 4; r++){
            float mx = fmaxf(fmaxf(sv[0][r], sv[1][r]), fmaxf(sv[2][r], sv[3][r]));
            #pragma unroll
            for (int msk = 1; msk < 16; msk <<= 1) mx = fmaxf(mx, __shfl_xor(mx, msk));
            float nm = fmaxf(rm[r], mx);
            float se = __expf(sv[0][r]-nm) + __expf(sv[1][r]-nm)
                     + __expf(sv[2][r]-nm) + __expf(sv[3][r]-nm);
            #pragma unroll
            for (int msk = 1; msk < 16; msk <<= 1) se += __shfl_xor(se, msk);
            rl[r] = rl[r] * __expf(rm[r] - nm) + se;
            rm[r] = nm;
        }
    }
    if (m == 0){
        #pragma unroll
        for (int r = 0; r < 4; r++){
            int k = k0 + w*16 + q*4 + r;
            long long idx = (long long)jc * (NB*HW) + (long long)b*HW + k;
            mpart[idx] = rm[r];
            lpart[idx] = rl[r];
        }
    }
}

// ---------------- combine partial softmax stats ----------------
__global__ void k_attn_comb(const float* __restrict__ mpart, const float* __restrict__ lpart,
                            float* __restrict__ mrow, float* __restrict__ ilrow){
    int i = blockIdx.x*256 + threadIdx.x;   // b*HW + k, total 16384
    float m0 = mpart[i], m1 = mpart[i+16384], m2 = mpart[i+32768], m3 = mpart[i+49152];
    float m = fmaxf(fmaxf(m0,m1), fmaxf(m2,m3));
    float l = lpart[i]*__expf(m0-m) + lpart[i+16384]*__expf(m1-m)
            + lpart[i+32768]*__expf(m2-m) + lpart[i+49152]*__expf(m3-m);
    mrow[i] = m;
    ilrow[i] = 1.f / l;
}

// ---------------- attention pass 2 (split-k): partial L ----------------
__global__ __launch_bounds__(256)
void k_attn_apply2(const unsigned short* __restrict__ QT,
                   const unsigned short* __restrict__ PT,
                   const unsigned short* __restrict__ Pb,
                   const float* __restrict__ mrow, const float* __restrict__ ilrow,
                   float* __restrict__ Lp){
    int b = blockIdx.z, kc = blockIdx.y, j0 = blockIdx.x * 64;
    const unsigned short* QTb = QT + (long long)b * HW * CO;
    const unsigned short* PTb = PT + (long long)b * HW * CO;
    const unsigned short* Pbb = Pb + (long long)b * CO * HW;
    const float* mb = mrow + (long long)b * HW;
    const float* lb = ilrow + (long long)b * HW;
    __shared__ unsigned short Qks[64][136];  // also Pjs during init (aliased)
    __shared__ unsigned short Pcs[128][72];
    __shared__ unsigned short Et[64][72];
    int t = threadIdx.x;
    int w = t >> 6, lane = t & 63, m = lane & 15, q = lane >> 4;
    {   // stage PT j-tile into Qks slot, read bj frags to registers
        int r = t >> 2, ch = t & 3;
        const uint4* src = (const uint4*)(PTb + (long long)(j0 + r) * CO + ch * 32);
        uint4* dst = (uint4*)&Qks[r][ch * 32];
        #pragma unroll
        for (int i = 0; i < 4; i++) dst[i] = src[i];
    }
    __syncthreads();
    s8v bj[4][4];
    #pragma unroll
    for (int ct = 0; ct < 4; ct++)
        #pragma unroll
        for (int ks = 0; ks < 4; ks++)
            bj[ct][ks] = *(const s8v*)&Qks[ct*16 + m][q*8 + ks*32];
    f4v accL[2][4];
    #pragma unroll
    for (int mt = 0; mt < 2; mt++)
        #pragma unroll
        for (int ct = 0; ct < 4; ct++){ f4v z = {0.f,0.f,0.f,0.f}; accL[mt][ct] = z; }
    const float scale = 0.015625f;
    int kbase = kc * 1024;
    for (int kt = 0; kt < 16; kt++){
        int k0 = kbase + kt*64;
        __syncthreads();
        {
            int r = t >> 2, ch = t & 3;
            const uint4* src = (const uint4*)(QTb + (long long)(k0 + r) * CO + ch * 32);
            uint4* dst = (uint4*)&Qks[r][ch * 32];
            #pragma unroll
            for (int i = 0; i < 4; i++) dst[i] = src[i];
        }
        {
            int c = t >> 1, hf = t & 1;
            const uint4* src = (const uint4*)(Pbb + (long long)c * HW + k0 + hf * 32);
            uint4* dst = (uint4*)&Pcs[c][hf * 32];
            #pragma unroll
            for (int i = 0; i < 4; i++) dst[i] = src[i];
        }
        __syncthreads();
        s8v aS[4];
        #pragma unroll
        for (int ks = 0; ks < 4; ks++) aS[ks] = *(const s8v*)&Qks[w*16 + m][q*8 + ks*32];
        float mk[4], il[4];
        #pragma unroll
        for (int r = 0; r < 4; r++){
            int kg = k0 + w*16 + q*4 + r;
            mk[r] = mb[kg]; il[r] = lb[kg];
        }
        #pragma unroll
        for (int ct = 0; ct < 4; ct++){
            f4v s = {0.f,0.f,0.f,0.f};
            #pragma unroll
            for (int ks = 0; ks < 4; ks++)
                s = __builtin_amdgcn_mfma_f32_16x16x32_bf16(aS[ks], bj[ct][ks], s, 0, 0, 0);
            s4v e4;
            #pragma unroll
            for (int r = 0; r < 4; r++)
                e4[r] = (short)f2bf(__expf(s[r]*scale - mk[r]) * il[r]);
            *(s4v*)&Et[ct*16 + m][w*16 + q*4] = e4;
        }
        __syncthreads();
        s8v aP[2][2];
        #pragma unroll
        for (int mt = 0; mt < 2; mt++)
            #pragma unroll
            for (int ks2 = 0; ks2 < 2; ks2++)
                aP[mt][ks2] = *(const s8v*)&Pcs[w*32 + mt*16 + m][q*8 + ks2*32];
        #pragma unroll
        for (int ct = 0; ct < 4; ct++){
            s8v bE0 = *(const s8v*)&Et[ct*16 + m][q*8];
            s8v bE1 = *(const s8v*)&Et[ct*16 + m][q*8 + 32];
            #pragma unroll
            for (int mt = 0; mt < 2; mt++){
                accL[mt][ct] = __builtin_amdgcn_mfma_f32_16x16x32_bf16(aP[mt][0], bE0, accL[mt][ct], 0, 0, 0);
                accL[mt][ct] = __builtin_amdgcn_mfma_f32_16x16x32_bf16(aP[mt][1], bE1, accL[mt][ct], 0, 0, 0);
            }
        }
    }
    float* Lpb = Lp + ((long long)(kc*NB + b) * CO) * HW;
    #pragma unroll
    for (int mt = 0; mt < 2; mt++)
        #pragma unroll
        for (int ct = 0; ct < 4; ct++)
            #pragma unroll
            for (int r = 0; r < 4; r++){
                int c = w*32 + mt*16 + q*4 + r;
                Lpb[(long long)c*HW + j0 + ct*16 + m] = accL[mt][ct][r];
            }
}

// ---------------- combine L partials + xa -> OT bf16 (transposed) ----------------
__global__ __launch_bounds__(256)
void k_attn_fin(const float* __restrict__ Lp, const float* __restrict__ xa,
                unsigned short* __restrict__ OT){
    int b = blockIdx.z, c0 = blockIdx.y*64, j0 = blockIdx.x*64;
    __shared__ unsigned short T[64][66];
    int t = threadIdx.x;
    int jl = t & 63, cs = t >> 6;
    const long long csz = (long long)NB*CO*HW;
    #pragma unroll
    for (int r = 0; r < 16; r++){
        int c = cs*16 + r;
        long long idx = ((long long)b*CO + c0 + c)*HW + j0 + jl;
        float v = xa[idx] + Lp[idx] + Lp[idx+csz] + Lp[idx+2*csz] + Lp[idx+3*csz];
        T[c][jl] = f2bf(v);
    }
    __syncthreads();
    int cl = t & 63, js = t >> 6;
    #pragma unroll
    for (int r = 0; r < 16; r++){
        int j = js*16 + r;
        OT[((long long)b*HW + j0 + j)*128 + c0 + cl] = T[cl][j];
    }
}

extern "C" void kernel_launch(void* const* d_in, const int* in_sizes, int n_in,
                              void* d_out, int out_size, void* d_ws, size_t ws_size,
                              hipStream_t stream) {
    const float* x       = (const float*)d_in[0];
    const float* conv1_w = (const float*)d_in[1];
    const float* conv1_b = (const float*)d_in[2];
    const float* conv2_w = (const float*)d_in[3];
    const float* conv2_b = (const float*)d_in[4];
    const float* cw_w1   = (const float*)d_in[5];
    const float* cw_b1   = (const float*)d_in[6];
    const float* cw_g    = (const float*)d_in[7];
    const float* cw_bt   = (const float*)d_in[8];
    const float* cw_w2   = (const float*)d_in[9];
    const float* cw_b2   = (const float*)d_in[10];
    const float* a0_w    = (const float*)d_in[11];
    const float* a0_g    = (const float*)d_in[12];
    const float* a0_b    = (const float*)d_in[13];
    const float* a1_w    = (const float*)d_in[14];
    const float* a1_g    = (const float*)d_in[15];
    const float* a1_b    = (const float*)d_in[16];
    const float* a2_w    = (const float*)d_in[17];
    const float* a2_g    = (const float*)d_in[18];
    const float* a2_b    = (const float*)d_in[19];
    const float* a3_w    = (const float*)d_in[20];
    const float* a3_g    = (const float*)d_in[21];
    const float* a3_b    = (const float*)d_in[22];
    const float* ap_w    = (const float*)d_in[23];
    const float* ap_g    = (const float*)d_in[24];
    const float* ap_b    = (const float*)d_in[25];
    const float* pj_w    = (const float*)d_in[26];
    const float* pj_g    = (const float*)d_in[27];
    const float* pj_b    = (const float*)d_in[28];
    float* out = (float*)d_out;

    // ---- workspace layout ----
    float* ws    = (float*)d_ws;
    float* avg   = ws;                  // 1024
    float* mx    = ws + 1024;           // 1024
    float* sv    = ws + 2048;           // 1024
    float* gp    = ws + 3072;           // 1024
    float* bp    = ws + 4096;           // 1024
    float* mrow  = ws + 5120;           // 16384
    float* ilrow = ws + 21504;          // 16384
    float* xa    = ws + 37888;          // 2,097,152
    float* mpart = xa + 2097152;        // 65536 (old O slot)
    float* lpart = mpart + 65536;       // 65536
    unsigned short* sb = (unsigned short*)(ws + 4232192);
    unsigned short* xT    = sb;                    // 4,194,304
    unsigned short* xcT   = sb + 4194304;          // 4,194,304
    unsigned short* catT  = sb + 8388608;          // 20,971,520
    unsigned short* projT = sb + 29360128;         // 4,194,304
    unsigned short* P_bf  = sb + 33554432;         // 2,097,152
    unsigned short* PT_bf = sb + 35651584;         // 2,097,152
    unsigned short* QT_bf = sb + 37748736;         // 2,097,152
    unsigned short* OT_bf = sb + 39845888;         // 2,097,152
    unsigned short* w_c1  = sb + 41943040;         // 32768
    unsigned short* w_a0  = sb + 41975808;         // 65536
    unsigned short* w_pj  = sb + 42041344;         // 327680
    unsigned short* w_c2  = sb + 42369024;         // 32768
    unsigned short* w_d3  = sb + 42401792;         // 589824
    unsigned short* w_d6  = sb + 42991616;         // 589824
    unsigned short* w_d9  = sb + 43581440;         // 589824
    float* Lp = (float*)catT;           // alias: catT dead after proj; 16.8M floats fit in 21M shorts*2B

    // ---- stats + channel weighting ----
    k_rowstats<<<dim3(NB*CI), 256, 0, stream>>>(x, avg, mx);
    k_cw<<<dim3(NB), 256, 0, stream>>>(avg, mx, cw_w1, cw_b1, cw_g, cw_bt, cw_w2, cw_b2, sv, gp);

    // ---- weight casts ----
    k_wcast<<<dim3(128),  256, 0, stream>>>(conv1_w, w_c1);
    k_wcast<<<dim3(256),  256, 0, stream>>>(a0_w,    w_a0);
    k_wcast<<<dim3(1280), 256, 0, stream>>>(pj_w,    w_pj);
    k_wcast<<<dim3(128),  256, 0, stream>>>(conv2_w, w_c2);
    k_w3<<<dim3(2304), 256, 0, stream>>>(a1_w, w_d3);
    k_w3<<<dim3(2304), 256, 0, stream>>>(a2_w, w_d6);
    k_w3<<<dim3(2304), 256, 0, stream>>>(a3_w, w_d9);

    // ---- x -> xT bf16 and xcT ----
    k_xT<<<dim3(64, 4, NB), 256, 0, stream>>>(x, sv, xT, xcT);

    // ---- x1 = conv1(x)+b -> P_bf/PT_bf ----
    k_conv1m<<<dim3(64, NB), 256, 0, stream>>>(w_c1, xT, conv1_b, PT_bf, P_bf, nullptr);

    // ---- ASPP branches (fused conv+LN+GELU -> catT bf16) ----
    k_branch1<<<dim3(64, NB), 512, 0, stream>>>(w_a0, 256, xcT, a0_g, a0_b, catT, 1280, 0);
    k_branch3<<<dim3(64, NB), 512, 0, stream>>>(w_d3, xcT, 3, a1_g, a1_b, catT, 256);
    k_branch3<<<dim3(64, NB), 512, 0, stream>>>(w_d6, xcT, 6, a2_g, a2_b, catT, 512);
    k_branch3<<<dim3(64, NB), 512, 0, stream>>>(w_d9, xcT, 9, a3_g, a3_b, catT, 768);
    k_pool<<<dim3(NB), 256, 0, stream>>>(gp, ap_w, ap_g, ap_b, bp);
    k_bcastT<<<dim3(512, NB), 256, 0, stream>>>(bp, catT);

    // ---- proj = GELU(LN(conv1x1(cat))) -> projT bf16 ----
    k_branch1<<<dim3(64, NB), 512, 0, stream>>>(w_pj, 1280, catT, pj_g, pj_b, projT, 256, 0);

    // ---- xa = conv1(proj)+b -> xa f32 + QT_bf ----
    k_conv1m<<<dim3(64, NB), 256, 0, stream>>>(w_c1, projT, conv1_b, QT_bf, nullptr, xa);

    // ---- attention (split-j stats, split-k apply, fused combine) ----
    k_attn_stats2<<<dim3(64, 4, NB), 256, 0, stream>>>(QT_bf, PT_bf, mpart, lpart);
    k_attn_comb<<<dim3(64), 256, 0, stream>>>(mpart, lpart, mrow, ilrow);
    k_attn_apply2<<<dim3(64, 4, NB), 256, 0, stream>>>(QT_bf, PT_bf, P_bf, mrow, ilrow, Lp);
    k_attn_fin<<<dim3(64, 2, NB), 256, 0, stream>>>(Lp, xa, OT_bf);

    // ---- out = conv2(O)+b ----
    k_gemm_out<<<dim3(64, NB), 256, 0, stream>>>(w_c2, OT_bf, conv2_b, out);

    (void)in_sizes; (void)n_in; (void)out_size; (void)ws_size;
}